// Round 1
// baseline (261.427 us; speedup 1.0000x reference)
//
#include <hip/hip_runtime.h>
#include <math.h>

#define NN 256
#define BB 1024
#define DD 64

// ---------------- K1: H = relu(x @ W_enc + b_enc)  (1024x64) ----------------
__global__ __launch_bounds__(256) void k1_enc(
    const float* __restrict__ x, const float* __restrict__ Wenc,
    const float* __restrict__ benc, float* __restrict__ H)
{
    int t = threadIdx.x;
    int d = t & 63;
    int b = (blockIdx.x << 2) + (t >> 6);
    const float* xr = x + b * NN;
    float acc = benc[d];
    for (int n = 0; n < NN; n += 4) {
        float4 xv = *(const float4*)&xr[n];
        acc = fmaf(xv.x, Wenc[(n + 0) * DD + d], acc);
        acc = fmaf(xv.y, Wenc[(n + 1) * DD + d], acc);
        acc = fmaf(xv.z, Wenc[(n + 2) * DD + d], acc);
        acc = fmaf(xv.w, Wenc[(n + 3) * DD + d], acc);
    }
    H[b * DD + d] = fmaxf(acc, 0.0f);
}

// ---------------- K2: z = mu + eps*exp(0.5*logvar), stored transposed ZT[n][b]
__global__ __launch_bounds__(256) void k2_z(
    const float* __restrict__ H, const float* __restrict__ Wmu,
    const float* __restrict__ bmu, const float* __restrict__ Wlv,
    const float* __restrict__ blv, const float* __restrict__ eps,
    float* __restrict__ ZT)
{
    __shared__ float Hs[4][DD];
    int t = threadIdx.x;
    int b0 = blockIdx.x << 2;
    Hs[t >> 6][t & 63] = H[((b0 + (t >> 6)) << 6) + (t & 63)];
    __syncthreads();
    int n = t;
    float mu[4], lv[4];
    float bm = bmu[n], bl = blv[n];
#pragma unroll
    for (int i = 0; i < 4; ++i) { mu[i] = bm; lv[i] = bl; }
    for (int d = 0; d < DD; ++d) {
        float wm = Wmu[d * NN + n];
        float wl = Wlv[d * NN + n];
#pragma unroll
        for (int i = 0; i < 4; ++i) {
            float h = Hs[i][d];
            mu[i] = fmaf(h, wm, mu[i]);
            lv[i] = fmaf(h, wl, lv[i]);
        }
    }
#pragma unroll
    for (int i = 0; i < 4; ++i) {
        int b = b0 + i;
        float z = fmaf(eps[b * NN + n], expf(0.5f * lv[i]), mu[i]);
        ZT[n * BB + b] = z;
    }
}

// ---------------- K3a: adj rows (sigmoid + forced self-loop + threshold), deg_out
__global__ __launch_bounds__(256) void k3a(
    const float* __restrict__ gl, const int* __restrict__ itp,
    float* __restrict__ adj, float* __restrict__ dego)
{
    int nrow = blockIdx.x, m = threadIdx.x;
    float v = gl[nrow * NN + m];
    float a = (nrow == m) ? 1.0f : 1.0f / (1.0f + expf(-v));
    if (itp[0] > 50 && !(a > 0.1f)) a = 0.0f;
    adj[nrow * NN + m] = a;
    unsigned long long ball = __ballot(a != 0.0f);
    __shared__ int cnt_s[4];
    if ((m & 63) == 0) cnt_s[m >> 6] = __popcll(ball);
    __syncthreads();
    if (m == 0) dego[nrow] = (float)(cnt_s[0] + cnt_s[1] + cnt_s[2] + cnt_s[3]);
}

// ---------------- K3b: deg_in per column + normalized ADJW[n][m] --------------
__global__ __launch_bounds__(256) void k3b(
    const float* __restrict__ adj, const float* __restrict__ dego,
    float* __restrict__ adjw)
{
    int m = blockIdx.x, nrow = threadIdx.x;
    float a = adj[nrow * NN + m];
    unsigned long long ball = __ballot(a != 0.0f);
    __shared__ int cnt_s[4];
    __shared__ float din_s;
    if ((nrow & 63) == 0) cnt_s[nrow >> 6] = __popcll(ball);
    __syncthreads();
    if (nrow == 0) din_s = (float)(cnt_s[0] + cnt_s[1] + cnt_s[2] + cnt_s[3]);
    __syncthreads();
    float w = a * (1.0f / sqrtf(dego[nrow])) * (1.0f / sqrtf(din_s));
    adjw[nrow * NN + m] = w;
}

// ---------------- K4: E = tanh(z*A + C); P1T[n][b][k] = E @ gc1_W -------------
// grid 2048 = 256 n  x  8 b-tiles of 128
__global__ __launch_bounds__(256) void k4_emb_p1(
    const float* __restrict__ ZT, const float* __restrict__ embW,
    const float* __restrict__ embB, const float* __restrict__ g1W,
    float* __restrict__ P1T)
{
    __shared__ __align__(16) float Ew[128][68];   // +4 pad: conflict-free frag reads
    __shared__ __align__(16) float Wt[32][68];    // gc1_W transposed [k][d]
    __shared__ float Asb[64], Csb[64];
    int t = threadIdx.x;
    int nn = blockIdx.x & 255;
    int b0 = (blockIdx.x >> 8) << 7;
    size_t ebase = (size_t)nn * (257 * 64);
    if (t < 64) {
        Asb[t] = embW[ebase + t];                                  // emb_W[n,0,d]
        Csb[t] = embW[ebase + ((size_t)(nn + 1) << 6) + t]         // emb_W[n,n+1,d]
               + embB[(nn << 6) + t];
    }
    for (int i = t; i < 2048; i += 256) {
        int k = i >> 6, d = i & 63;
        Wt[k][d] = g1W[d * 32 + k];
    }
    __syncthreads();
    for (int i = 0; i < 32; ++i) {                // phase 1: 128x64 E tile
        int idx = (i << 8) + t;
        int b = idx >> 6, d = idx & 63;
        float z = ZT[nn * BB + b0 + b];
        Ew[b][d] = tanhf(fmaf(z, Asb[d], Csb[d]));
    }
    __syncthreads();
    int kg = t & 7, bg = t >> 3;                  // 32 b-groups x 8 k-groups
    float acc[4][4];
#pragma unroll
    for (int i = 0; i < 4; ++i)
#pragma unroll
        for (int j = 0; j < 4; ++j) acc[i][j] = 0.0f;
#pragma unroll
    for (int dd = 0; dd < 64; dd += 4) {
        float4 e[4], w[4];
#pragma unroll
        for (int bi = 0; bi < 4; ++bi) e[bi] = *(const float4*)&Ew[bg + (bi << 5)][dd];
#pragma unroll
        for (int ki = 0; ki < 4; ++ki) w[ki] = *(const float4*)&Wt[kg + (ki << 3)][dd];
#pragma unroll
        for (int bi = 0; bi < 4; ++bi)
#pragma unroll
            for (int ki = 0; ki < 4; ++ki) {
                acc[bi][ki] = fmaf(e[bi].x, w[ki].x, acc[bi][ki]);
                acc[bi][ki] = fmaf(e[bi].y, w[ki].y, acc[bi][ki]);
                acc[bi][ki] = fmaf(e[bi].z, w[ki].z, acc[bi][ki]);
                acc[bi][ki] = fmaf(e[bi].w, w[ki].w, acc[bi][ki]);
            }
    }
#pragma unroll
    for (int bi = 0; bi < 4; ++bi) {              // k set = {kg + 8*ki}
        int b = b0 + bg + (bi << 5);
        float* dst = &P1T[(size_t)nn * 32768 + (b << 5) + kg];
        dst[0]  = acc[bi][0];
        dst[8]  = acc[bi][1];
        dst[16] = acc[bi][2];
        dst[24] = acc[bi][3];
    }
}

// ---------------- K5: AGG1 = ADJW^T @ P1T, fused tanh+gc2 dot -> Q[b][m] ------
// C[m][j], j=b*32+k.  128x128 tile, 8x8 micro, BK=8, reg-prefetch.
// grid 512 = 256 j-tiles x 2 m-tiles
__global__ __launch_bounds__(256) void k5_gc1(
    const float* __restrict__ adjw, const float* __restrict__ P1T,
    const float* __restrict__ g1b, const float* __restrict__ g2W,
    float* __restrict__ Q)
{
    __shared__ __align__(16) float At[8][128];
    __shared__ __align__(16) float Bt[8][128];
    int t = threadIdx.x;
    int tx = t & 15, ty = t >> 4;
    int mt = blockIdx.x & 1;
    int jt = blockIdx.x >> 1;
    int m0 = mt << 7;
    int j0 = jt << 7;
    int skk = t >> 5, sc = t & 31;

    float acc[8][8];
#pragma unroll
    for (int i = 0; i < 8; ++i)
#pragma unroll
        for (int j = 0; j < 8; ++j) acc[i][j] = 0.0f;

    float4 an = *(const float4*)&adjw[skk * NN + m0 + (sc << 2)];
    float4 bn = *(const float4*)&P1T[(size_t)skk * 32768 + j0 + (sc << 2)];

    for (int nb = 0; nb < NN; nb += 8) {
        *(float4*)&At[skk][sc << 2] = an;
        *(float4*)&Bt[skk][sc << 2] = bn;
        __syncthreads();
        if (nb + 8 < NN) {        // prefetch next K-slice under compute
            an = *(const float4*)&adjw[(nb + 8 + skk) * NN + m0 + (sc << 2)];
            bn = *(const float4*)&P1T[(size_t)(nb + 8 + skk) * 32768 + j0 + (sc << 2)];
        }
#pragma unroll
        for (int kk = 0; kk < 8; ++kk) {
            float4 a0 = *(const float4*)&At[kk][ty << 2];
            float4 a1 = *(const float4*)&At[kk][64 + (ty << 2)];
            float4 bq0 = *(const float4*)&Bt[kk][tx << 2];
            float4 bq1 = *(const float4*)&Bt[kk][64 + (tx << 2)];
            float am[8] = {a0.x, a0.y, a0.z, a0.w, a1.x, a1.y, a1.z, a1.w};
            float bj[8] = {bq0.x, bq0.y, bq0.z, bq0.w, bq1.x, bq1.y, bq1.z, bq1.w};
#pragma unroll
            for (int i = 0; i < 8; ++i)
#pragma unroll
                for (int j = 0; j < 8; ++j)
                    acc[i][j] = fmaf(am[i], bj[j], acc[i][j]);
        }
        __syncthreads();
    }
    // epilogue: h1 = tanh(acc + gc1_b[k]); Q[b][m] = sum_k h1 * gc2_W[k]
    int k0 = (tx & 7) << 2;
    float g2[4], b1v[4];
#pragma unroll
    for (int i = 0; i < 4; ++i) { g2[i] = g2W[k0 + i]; b1v[i] = g1b[k0 + i]; }
#pragma unroll
    for (int jh = 0; jh < 2; ++jh) {
        int b = (jt << 2) + (jh << 1) + (tx >> 3);
#pragma unroll
        for (int mh = 0; mh < 2; ++mh) {
            float red[4];
#pragma unroll
            for (int mi = 0; mi < 4; ++mi) {
                int ai = (mh << 2) + mi;
                float s = 0.0f;
#pragma unroll
                for (int ji = 0; ji < 4; ++ji)
                    s += tanhf(acc[ai][(jh << 2) + ji] + b1v[ji]) * g2[ji];
                s += __shfl_xor(s, 1);
                s += __shfl_xor(s, 2);
                s += __shfl_xor(s, 4);
                red[mi] = s;
            }
            if ((tx & 7) == 0) {
                *(float4*)&Q[b * NN + m0 + (mh << 6) + (ty << 2)] =
                    make_float4(red[0], red[1], red[2], red[3]);
            }
        }
    }
}

// ---------------- K6: x_hat = Q @ ADJW + gc2_b  (1024x256 @ 256x256) ----------
// grid 64 = 16 b-tiles x 4 m'-tiles, 64x64 tile, 4x4 micro
__global__ __launch_bounds__(256) void k6_gc2(
    const float* __restrict__ Q, const float* __restrict__ adjw,
    const float* __restrict__ g2b, float* __restrict__ xh)
{
    __shared__ float At[64][17];                 // [b_local][kk], padded
    __shared__ __align__(16) float Bt[16][64];   // [kk][m'_local]
    int t = threadIdx.x;
    int tx = t & 15, ty = t >> 4;
    int mt = blockIdx.x & 3, bt = blockIdx.x >> 2;
    int m0 = mt << 6, b0 = bt << 6;
    float acc[4][4];
#pragma unroll
    for (int i = 0; i < 4; ++i)
#pragma unroll
        for (int j = 0; j < 4; ++j) acc[i][j] = 0.0f;

    for (int kb = 0; kb < NN; kb += 16) {
        for (int i = t; i < 1024; i += 256) {
            int kk = i & 15, c = i >> 4;
            At[c][kk] = Q[(b0 + c) * NN + kb + kk];
        }
        for (int i = t; i < 1024; i += 256) {
            int mj = i & 63, kk = i >> 6;
            Bt[kk][mj] = adjw[(kb + kk) * NN + m0 + mj];
        }
        __syncthreads();
#pragma unroll
        for (int kk = 0; kk < 16; ++kk) {
            float4 bq = *(const float4*)&Bt[kk][tx << 2];
            float am[4];
#pragma unroll
            for (int bi = 0; bi < 4; ++bi) am[bi] = At[(ty << 2) + bi][kk];
#pragma unroll
            for (int bi = 0; bi < 4; ++bi) {
                acc[bi][0] = fmaf(am[bi], bq.x, acc[bi][0]);
                acc[bi][1] = fmaf(am[bi], bq.y, acc[bi][1]);
                acc[bi][2] = fmaf(am[bi], bq.z, acc[bi][2]);
                acc[bi][3] = fmaf(am[bi], bq.w, acc[bi][3]);
            }
        }
        __syncthreads();
    }
    float bias = g2b[0];
#pragma unroll
    for (int bi = 0; bi < 4; ++bi) {
        float4 v = make_float4(acc[bi][0] + bias, acc[bi][1] + bias,
                               acc[bi][2] + bias, acc[bi][3] + bias);
        *(float4*)&xh[(b0 + (ty << 2) + bi) * NN + m0 + (tx << 2)] = v;
    }
}

extern "C" void kernel_launch(void* const* d_in, const int* in_sizes, int n_in,
                              void* d_out, int out_size, void* d_ws, size_t ws_size,
                              hipStream_t stream) {
    const float* x    = (const float*)d_in[0];
    const float* eps  = (const float*)d_in[1];
    const float* gl   = (const float*)d_in[2];
    const float* Wenc = (const float*)d_in[3];
    const float* benc = (const float*)d_in[4];
    const float* Wmu  = (const float*)d_in[5];
    const float* bmu  = (const float*)d_in[6];
    const float* Wlv  = (const float*)d_in[7];
    const float* blv  = (const float*)d_in[8];
    const float* embW = (const float*)d_in[9];
    const float* embB = (const float*)d_in[10];
    const float* g1W  = (const float*)d_in[11];
    const float* g1b  = (const float*)d_in[12];
    const float* g2W  = (const float*)d_in[13];
    const float* g2b  = (const float*)d_in[14];
    const int*   itp  = (const int*)d_in[15];

    float* ws   = (float*)d_ws;
    float* H    = ws;                 // 65536
    float* ZT   = ws + 65536;         // 262144
    float* ADJR = ws + 327680;        // 65536
    float* DEGO = ws + 393216;        // 256
    float* ADJW = ws + 393472;        // 65536
    float* P1T  = ws + 459008;        // 8388608  (n, b, k) = (256, 1024, 32)
    float* Qb   = ws + 8847616;       // 262144   (b, m)
    float* xh   = (float*)d_out;

    k1_enc  <<<256,  256, 0, stream>>>(x, Wenc, benc, H);
    k2_z    <<<256,  256, 0, stream>>>(H, Wmu, bmu, Wlv, blv, eps, ZT);
    k3a     <<<256,  256, 0, stream>>>(gl, itp, ADJR, DEGO);
    k3b     <<<256,  256, 0, stream>>>(ADJR, DEGO, ADJW);
    k4_emb_p1<<<2048,256, 0, stream>>>(ZT, embW, embB, g1W, P1T);
    k5_gc1  <<<512,  256, 0, stream>>>(ADJW, P1T, g1b, g2W, Qb);
    k6_gc2  <<<64,   256, 0, stream>>>(Qb, ADJW, g2b, xh);
}

// Round 4
// 229.592 us; speedup vs baseline: 1.1387x; 1.1387x over previous
//
#include <hip/hip_runtime.h>
#include <hip/hip_bf16.h>
#include <math.h>

#define NN 256
#define BB 1024
#define DD 64

typedef short bf16x8 __attribute__((ext_vector_type(8)));
typedef float f32x4 __attribute__((ext_vector_type(4)));

__device__ __forceinline__ float ftanh(float x) {
    // tanh(x) = 1 - 2/(e^{2x}+1); native exp + native rcp (~1e-7 abs err)
    float e = __expf(2.0f * x);
    return 1.0f - 2.0f * __builtin_amdgcn_rcpf(e + 1.0f);
}

__device__ __forceinline__ unsigned short f2bf(float v) {
    __hip_bfloat16 h = __float2bfloat16(v);
    return *reinterpret_cast<unsigned short*>(&h);
}

// ---------------- K1: H = relu(x @ W_enc + b_enc)  (1024x64) ----------------
__global__ __launch_bounds__(256) void k1_enc(
    const float* __restrict__ x, const float* __restrict__ Wenc,
    const float* __restrict__ benc, float* __restrict__ H)
{
    int t = threadIdx.x;
    int d = t & 63;
    int b = (blockIdx.x << 2) + (t >> 6);
    const float* xr = x + b * NN;
    float acc = benc[d];
    for (int n = 0; n < NN; n += 4) {
        float4 xv = *(const float4*)&xr[n];
        acc = fmaf(xv.x, Wenc[(n + 0) * DD + d], acc);
        acc = fmaf(xv.y, Wenc[(n + 1) * DD + d], acc);
        acc = fmaf(xv.z, Wenc[(n + 2) * DD + d], acc);
        acc = fmaf(xv.w, Wenc[(n + 3) * DD + d], acc);
    }
    H[b * DD + d] = fmaxf(acc, 0.0f);
}

// ---------------- K2: z = mu + eps*exp(0.5*logvar), stored transposed ZT[n][b]
__global__ __launch_bounds__(256) void k2_z(
    const float* __restrict__ H, const float* __restrict__ Wmu,
    const float* __restrict__ bmu, const float* __restrict__ Wlv,
    const float* __restrict__ blv, const float* __restrict__ eps,
    float* __restrict__ ZT)
{
    __shared__ float Hs[4][DD];
    int t = threadIdx.x;
    int b0 = blockIdx.x << 2;
    Hs[t >> 6][t & 63] = H[((b0 + (t >> 6)) << 6) + (t & 63)];
    __syncthreads();
    int n = t;
    float mu[4], lv[4];
    float bm = bmu[n], bl = blv[n];
#pragma unroll
    for (int i = 0; i < 4; ++i) { mu[i] = bm; lv[i] = bl; }
    for (int d = 0; d < DD; ++d) {
        float wm = Wmu[d * NN + n];
        float wl = Wlv[d * NN + n];
#pragma unroll
        for (int i = 0; i < 4; ++i) {
            float h = Hs[i][d];
            mu[i] = fmaf(h, wm, mu[i]);
            lv[i] = fmaf(h, wl, lv[i]);
        }
    }
#pragma unroll
    for (int i = 0; i < 4; ++i) {
        int b = b0 + i;
        float z = fmaf(eps[b * NN + n], expf(0.5f * lv[i]), mu[i]);
        ZT[n * BB + b] = z;
    }
}

// ---------------- K3a: adj rows (sigmoid + forced self-loop + threshold), deg_out
__global__ __launch_bounds__(256) void k3a(
    const float* __restrict__ gl, const int* __restrict__ itp,
    float* __restrict__ adj, float* __restrict__ dego)
{
    int nrow = blockIdx.x, m = threadIdx.x;
    float v = gl[nrow * NN + m];
    float a = (nrow == m) ? 1.0f : 1.0f / (1.0f + expf(-v));
    if (itp[0] > 50 && !(a > 0.1f)) a = 0.0f;
    adj[nrow * NN + m] = a;
    unsigned long long ball = __ballot(a != 0.0f);
    __shared__ int cnt_s[4];
    if ((m & 63) == 0) cnt_s[m >> 6] = __popcll(ball);
    __syncthreads();
    if (m == 0) dego[nrow] = (float)(cnt_s[0] + cnt_s[1] + cnt_s[2] + cnt_s[3]);
}

// ---------------- K3b: deg_in + normalized ADJW[n][m] + bf16 ADJWT[m][n] ------
__global__ __launch_bounds__(256) void k3b(
    const float* __restrict__ adj, const float* __restrict__ dego,
    float* __restrict__ adjw, unsigned short* __restrict__ adjwt)
{
    int m = blockIdx.x, nrow = threadIdx.x;
    float a = adj[nrow * NN + m];
    unsigned long long ball = __ballot(a != 0.0f);
    __shared__ int cnt_s[4];
    __shared__ float din_s;
    if ((nrow & 63) == 0) cnt_s[nrow >> 6] = __popcll(ball);
    __syncthreads();
    if (nrow == 0) din_s = (float)(cnt_s[0] + cnt_s[1] + cnt_s[2] + cnt_s[3]);
    __syncthreads();
    float w = a * (1.0f / sqrtf(dego[nrow])) * (1.0f / sqrtf(din_s));
    adjw[nrow * NN + m] = w;          // f32 [n][m] for K6
    adjwt[m * NN + nrow] = f2bf(w);   // bf16 [m][n] (K-contig) for K5 A-operand
}

// ---------------- K4: E = tanh(z*A + C); P1TT[j][n] = bf16(E @ gc1_W) ---------
// block = (nc: 32 n's, bt: 4 b's); grid 2048 = 8 nc x 256 bt
// E rows r = bl*32 + ni  (bl = b-local 0..3, ni = n-local 0..31)
__global__ __launch_bounds__(256) void k4_emb_p1(
    const float* __restrict__ ZT, const float* __restrict__ embW,
    const float* __restrict__ embB, const float* __restrict__ g1W,
    unsigned short* __restrict__ P1TT)
{
    __shared__ float As[32][68], Cs[32][68];      // per-n alpha, const
    __shared__ float Wt[32][68];                  // gc1_W transposed [k][d]
    __shared__ float zs[32][4];
    __shared__ __align__(16) float Ew[128][68];
    int t = threadIdx.x;
    int nc = blockIdx.x >> 8;
    int bt = blockIdx.x & 255;
    int n0 = nc << 5, b0 = bt << 2;
    for (int i = t; i < 2048; i += 256) {
        int ni = i >> 6, d = i & 63;
        size_t eb = (size_t)(n0 + ni) * (257 * 64);
        As[ni][d] = embW[eb + d];                                    // emb_W[n,0,d]
        Cs[ni][d] = embW[eb + ((size_t)(n0 + ni + 1) << 6) + d]      // emb_W[n,n+1,d]
                  + embB[((n0 + ni) << 6) + d];
    }
    for (int i = t; i < 2048; i += 256) {
        int k = i >> 6, d = i & 63;
        Wt[k][d] = g1W[d * 32 + k];
    }
    if (t < 128) zs[t >> 2][t & 3] = ZT[(size_t)(n0 + (t >> 2)) * BB + b0 + (t & 3)];
    __syncthreads();
#pragma unroll
    for (int i = 0; i < 32; ++i) {                // phase 1: 128x64 E tile
        int idx = (i << 8) + t;
        int r = idx >> 6, d = idx & 63;
        int ni = r & 31, bl = r >> 5;
        Ew[r][d] = ftanh(fmaf(zs[ni][bl], As[ni][d], Cs[ni][d]));
    }
    __syncthreads();
    int kg = t & 7, bg = t >> 3;                  // 32 row-groups x 8 k-groups
    float acc[4][4];
#pragma unroll
    for (int i = 0; i < 4; ++i)
#pragma unroll
        for (int j = 0; j < 4; ++j) acc[i][j] = 0.0f;
#pragma unroll
    for (int dd = 0; dd < 64; dd += 4) {
        float4 e[4], w[4];
#pragma unroll
        for (int bi = 0; bi < 4; ++bi) e[bi] = *(const float4*)&Ew[bg + (bi << 5)][dd];
#pragma unroll
        for (int ki = 0; ki < 4; ++ki) w[ki] = *(const float4*)&Wt[kg + (ki << 3)][dd];
#pragma unroll
        for (int bi = 0; bi < 4; ++bi)
#pragma unroll
            for (int ki = 0; ki < 4; ++ki) {
                acc[bi][ki] = fmaf(e[bi].x, w[ki].x, acc[bi][ki]);
                acc[bi][ki] = fmaf(e[bi].y, w[ki].y, acc[bi][ki]);
                acc[bi][ki] = fmaf(e[bi].z, w[ki].z, acc[bi][ki]);
                acc[bi][ki] = fmaf(e[bi].w, w[ki].w, acc[bi][ki]);
            }
    }
    // epilogue: row bg+32bi -> (ni=bg, bl=bi); j = (b0+bl)*32 + kg + 8ki
#pragma unroll
    for (int bi = 0; bi < 4; ++bi) {
        size_t jb = ((size_t)((b0 + bi) << 5) + kg) * NN + n0 + bg;
#pragma unroll
        for (int ki = 0; ki < 4; ++ki)
            P1TT[jb + ((size_t)(ki << 3) * NN)] = f2bf(acc[bi][ki]);
    }
}

// ---------------- K5: AGG1 = ADJWT @ P1TT^T via bf16 MFMA, fused epilogue -----
// C[m][j], j = b*32+k.  Block: 64 j-cols x 256 m, 4 waves (wave w: m-frags 4w..4w+3).
// No LDS: A-frag and B-frag are each one dwordx4 load (K-contiguous bf16 layouts).
__global__ __launch_bounds__(256) void k5_mfma(
    const unsigned short* __restrict__ adjwt, const unsigned short* __restrict__ p1tt,
    const float* __restrict__ g1b, const float* __restrict__ g2w,
    float* __restrict__ Q)
{
    int t = threadIdx.x;
    int w = t >> 6, l = t & 63;
    int c = l & 15, q = l >> 4;       // frag col, k-quarter
    int j0 = blockIdx.x << 6;
    int mbase = w << 6;

    f32x4 acc[4][4];                  // [mi][ji]
#pragma unroll
    for (int i = 0; i < 4; ++i)
#pragma unroll
        for (int j = 0; j < 4; ++j) acc[i][j] = (f32x4)0.0f;

    const unsigned short* ap[4];
    const unsigned short* bp[4];
#pragma unroll
    for (int mi = 0; mi < 4; ++mi)
        ap[mi] = adjwt + (size_t)(mbase + (mi << 4) + c) * NN + (q << 3);
#pragma unroll
    for (int ji = 0; ji < 4; ++ji)
        bp[ji] = p1tt + (size_t)(j0 + (ji << 4) + c) * NN + (q << 3);

#pragma unroll 2
    for (int n0 = 0; n0 < NN; n0 += 32) {
        bf16x8 af[4], bf[4];
#pragma unroll
        for (int mi = 0; mi < 4; ++mi) af[mi] = *(const bf16x8*)(ap[mi] + n0);
#pragma unroll
        for (int ji = 0; ji < 4; ++ji) bf[ji] = *(const bf16x8*)(bp[ji] + n0);
#pragma unroll
        for (int mi = 0; mi < 4; ++mi)
#pragma unroll
            for (int ji = 0; ji < 4; ++ji)
                acc[mi][ji] = __builtin_amdgcn_mfma_f32_16x16x32_bf16(
                    af[mi], bf[ji], acc[mi][ji], 0, 0, 0);
    }

    // epilogue: ji -> (b = j0/32 + (ji>>1), k = (ji&1)*16 + c)
    // D frag: lane holds rows (q*4 + r), col c. Q[b][m] = sum_k tanh(D+g1b[k])*g2w[k]
    float b1v0 = g1b[c],      g2v0 = g2w[c];
    float b1v1 = g1b[16 + c], g2v1 = g2w[16 + c];
    int bb0 = blockIdx.x << 1;
#pragma unroll
    for (int mi = 0; mi < 4; ++mi) {
#pragma unroll
        for (int bb = 0; bb < 2; ++bb) {
            float red[4];
#pragma unroll
            for (int r = 0; r < 4; ++r) {
                float s = ftanh(acc[mi][(bb << 1) + 0][r] + b1v0) * g2v0
                        + ftanh(acc[mi][(bb << 1) + 1][r] + b1v1) * g2v1;
                s += __shfl_xor(s, 1);
                s += __shfl_xor(s, 2);
                s += __shfl_xor(s, 4);
                s += __shfl_xor(s, 8);
                red[r] = s;
            }
            float* qp = &Q[(size_t)(bb0 + bb) * NN + mbase + (mi << 4) + (q << 2)];
            if (c == 0) qp[0] = red[0];
            if (c == 1) qp[1] = red[1];
            if (c == 2) qp[2] = red[2];
            if (c == 3) qp[3] = red[3];
        }
    }
}

// ---------------- K6: x_hat = Q @ ADJW + gc2_b  (1024x256 @ 256x256) ----------
__global__ __launch_bounds__(256) void k6_gc2(
    const float* __restrict__ Q, const float* __restrict__ adjw,
    const float* __restrict__ g2b, float* __restrict__ xh)
{
    __shared__ float At[64][17];
    __shared__ __align__(16) float Bt[16][64];
    int t = threadIdx.x;
    int tx = t & 15, ty = t >> 4;
    int mt = blockIdx.x & 3, bt = blockIdx.x >> 2;
    int m0 = mt << 6, b0 = bt << 6;
    float acc[4][4];
#pragma unroll
    for (int i = 0; i < 4; ++i)
#pragma unroll
        for (int j = 0; j < 4; ++j) acc[i][j] = 0.0f;

    for (int kb = 0; kb < NN; kb += 16) {
        for (int i = t; i < 1024; i += 256) {
            int kk = i & 15, c = i >> 4;
            At[c][kk] = Q[(b0 + c) * NN + kb + kk];
        }
        for (int i = t; i < 1024; i += 256) {
            int mj = i & 63, kk = i >> 6;
            Bt[kk][mj] = adjw[(kb + kk) * NN + m0 + mj];
        }
        __syncthreads();
#pragma unroll
        for (int kk = 0; kk < 16; ++kk) {
            float4 bq = *(const float4*)&Bt[kk][tx << 2];
            float am[4];
#pragma unroll
            for (int bi = 0; bi < 4; ++bi) am[bi] = At[(ty << 2) + bi][kk];
#pragma unroll
            for (int bi = 0; bi < 4; ++bi) {
                acc[bi][0] = fmaf(am[bi], bq.x, acc[bi][0]);
                acc[bi][1] = fmaf(am[bi], bq.y, acc[bi][1]);
                acc[bi][2] = fmaf(am[bi], bq.z, acc[bi][2]);
                acc[bi][3] = fmaf(am[bi], bq.w, acc[bi][3]);
            }
        }
        __syncthreads();
    }
    float bias = g2b[0];
#pragma unroll
    for (int bi = 0; bi < 4; ++bi) {
        float4 v = make_float4(acc[bi][0] + bias, acc[bi][1] + bias,
                               acc[bi][2] + bias, acc[bi][3] + bias);
        *(float4*)&xh[(b0 + (ty << 2) + bi) * NN + m0 + (tx << 2)] = v;
    }
}

extern "C" void kernel_launch(void* const* d_in, const int* in_sizes, int n_in,
                              void* d_out, int out_size, void* d_ws, size_t ws_size,
                              hipStream_t stream) {
    const float* x    = (const float*)d_in[0];
    const float* eps  = (const float*)d_in[1];
    const float* gl   = (const float*)d_in[2];
    const float* Wenc = (const float*)d_in[3];
    const float* benc = (const float*)d_in[4];
    const float* Wmu  = (const float*)d_in[5];
    const float* bmu  = (const float*)d_in[6];
    const float* Wlv  = (const float*)d_in[7];
    const float* blv  = (const float*)d_in[8];
    const float* embW = (const float*)d_in[9];
    const float* embB = (const float*)d_in[10];
    const float* g1W  = (const float*)d_in[11];
    const float* g1b  = (const float*)d_in[12];
    const float* g2W  = (const float*)d_in[13];
    const float* g2b  = (const float*)d_in[14];
    const int*   itp  = (const int*)d_in[15];

    float* ws   = (float*)d_ws;
    float* H    = ws;                                   // 65536 f
    float* ZT   = ws + 65536;                           // 262144 f
    float* ADJR = ws + 327680;                          // 65536 f
    float* DEGO = ws + 393216;                          // 256 f
    float* ADJW = ws + 393472;                          // 65536 f
    unsigned short* ADJWT = (unsigned short*)(ws + 459008);   // 65536 bf16
    unsigned short* P1TT  = (unsigned short*)(ws + 491776);   // 8388608 bf16 [j][n]
    float* Qb   = ws + 4686080;                         // 262144 f
    float* xh   = (float*)d_out;

    k1_enc   <<<256,  256, 0, stream>>>(x, Wenc, benc, H);
    k2_z     <<<256,  256, 0, stream>>>(H, Wmu, bmu, Wlv, blv, eps, ZT);
    k3a      <<<256,  256, 0, stream>>>(gl, itp, ADJR, DEGO);
    k3b      <<<256,  256, 0, stream>>>(ADJR, DEGO, ADJW, ADJWT);
    k4_emb_p1<<<2048, 256, 0, stream>>>(ZT, embW, embB, g1W, P1TT);
    k5_mfma  <<<512,  256, 0, stream>>>(ADJWT, P1TT, g1b, g2W, Qb);
    k6_gc2   <<<64,   256, 0, stream>>>(Qb, ADJW, g2b, xh);
}

// Round 6
// 204.961 us; speedup vs baseline: 1.2755x; 1.1202x over previous
//
#include <hip/hip_runtime.h>
#include <hip/hip_bf16.h>
#include <math.h>

#define NN 256
#define BB 1024
#define DD 64

typedef short bf16x8 __attribute__((ext_vector_type(8)));
typedef float f32x4 __attribute__((ext_vector_type(4)));

__device__ __forceinline__ float ftanh(float x) {
    // tanh(x) = 1 - 2/(e^{2x}+1); native exp + native rcp (~1e-7 abs err)
    float e = __expf(2.0f * x);
    return 1.0f - 2.0f * __builtin_amdgcn_rcpf(e + 1.0f);
}

__device__ __forceinline__ unsigned short f2bf(float v) {
    __hip_bfloat16 h = __float2bfloat16(v);
    return *reinterpret_cast<unsigned short*>(&h);
}

__device__ __forceinline__ float bf2f(unsigned short u) {
    union { unsigned int i; float f; } c;
    c.i = ((unsigned int)u) << 16;
    return c.f;
}

// ---------------- K1: H = relu(x @ W_enc + b_enc)  (1024x64) ----------------
__global__ __launch_bounds__(256) void k1_enc(
    const float* __restrict__ x, const float* __restrict__ Wenc,
    const float* __restrict__ benc, float* __restrict__ H)
{
    int t = threadIdx.x;
    int d = t & 63;
    int b = (blockIdx.x << 2) + (t >> 6);
    const float* xr = x + b * NN;
    float acc = benc[d];
    for (int n = 0; n < NN; n += 4) {
        float4 xv = *(const float4*)&xr[n];
        acc = fmaf(xv.x, Wenc[(n + 0) * DD + d], acc);
        acc = fmaf(xv.y, Wenc[(n + 1) * DD + d], acc);
        acc = fmaf(xv.z, Wenc[(n + 2) * DD + d], acc);
        acc = fmaf(xv.w, Wenc[(n + 3) * DD + d], acc);
    }
    H[b * DD + d] = fmaxf(acc, 0.0f);
}

// ---------------- K2: z = mu + eps*exp(0.5*logvar), stored transposed ZT[n][b]
__global__ __launch_bounds__(256) void k2_z(
    const float* __restrict__ H, const float* __restrict__ Wmu,
    const float* __restrict__ bmu, const float* __restrict__ Wlv,
    const float* __restrict__ blv, const float* __restrict__ eps,
    float* __restrict__ ZT)
{
    __shared__ float Hs[4][DD];
    int t = threadIdx.x;
    int b0 = blockIdx.x << 2;
    Hs[t >> 6][t & 63] = H[((b0 + (t >> 6)) << 6) + (t & 63)];
    __syncthreads();
    int n = t;
    float mu[4], lv[4];
    float bm = bmu[n], bl = blv[n];
#pragma unroll
    for (int i = 0; i < 4; ++i) { mu[i] = bm; lv[i] = bl; }
    for (int d = 0; d < DD; ++d) {
        float wm = Wmu[d * NN + n];
        float wl = Wlv[d * NN + n];
#pragma unroll
        for (int i = 0; i < 4; ++i) {
            float h = Hs[i][d];
            mu[i] = fmaf(h, wm, mu[i]);
            lv[i] = fmaf(h, wl, lv[i]);
        }
    }
#pragma unroll
    for (int i = 0; i < 4; ++i) {
        int b = b0 + i;
        float z = fmaf(eps[b * NN + n], expf(0.5f * lv[i]), mu[i]);
        ZT[n * BB + b] = z;
    }
}

// ---------------- K3a: adj rows (sigmoid + forced self-loop + threshold), deg_out
__global__ __launch_bounds__(256) void k3a(
    const float* __restrict__ gl, const int* __restrict__ itp,
    float* __restrict__ adj, float* __restrict__ dego)
{
    int nrow = blockIdx.x, m = threadIdx.x;
    float v = gl[nrow * NN + m];
    float a = (nrow == m) ? 1.0f : 1.0f / (1.0f + expf(-v));
    if (itp[0] > 50 && !(a > 0.1f)) a = 0.0f;
    adj[nrow * NN + m] = a;
    unsigned long long ball = __ballot(a != 0.0f);
    __shared__ int cnt_s[4];
    if ((m & 63) == 0) cnt_s[m >> 6] = __popcll(ball);
    __syncthreads();
    if (m == 0) dego[nrow] = (float)(cnt_s[0] + cnt_s[1] + cnt_s[2] + cnt_s[3]);
}

// ---------------- K3b: deg_in + normalized ADJW[n][m] + bf16 ADJWT[m][n] ------
__global__ __launch_bounds__(256) void k3b(
    const float* __restrict__ adj, const float* __restrict__ dego,
    float* __restrict__ adjw, unsigned short* __restrict__ adjwt)
{
    int m = blockIdx.x, nrow = threadIdx.x;
    float a = adj[nrow * NN + m];
    unsigned long long ball = __ballot(a != 0.0f);
    __shared__ int cnt_s[4];
    __shared__ float din_s;
    if ((nrow & 63) == 0) cnt_s[nrow >> 6] = __popcll(ball);
    __syncthreads();
    if (nrow == 0) din_s = (float)(cnt_s[0] + cnt_s[1] + cnt_s[2] + cnt_s[3]);
    __syncthreads();
    float w = a * (1.0f / sqrtf(dego[nrow])) * (1.0f / sqrtf(din_s));
    adjw[nrow * NN + m] = w;          // f32 [n][m] for K6
    adjwt[m * NN + nrow] = f2bf(w);   // bf16 [m][n] (K-contig) for K5 A-operand
}

// ---------------- K4: P1TT[j][n] = bf16( tanh(z*A+C) @ gc1_W ) via MFMA -------
// Block: 8 n x 64 b, 256 thr (4 waves), grid 512 = 32 n-groups x 16 b-groups.
// E generated in registers directly in A-frag layout; split-bf16 (hi/lo) MFMA
// keeps f32-level accuracy: acc += Ehi*Whi + Elo*Whi + Ehi*Wlo.
// D-frags staged in LDS [64b][32k][8n] -> 16B dwordx4 global writes.
__global__ __launch_bounds__(256) void k4_mfma(
    const float* __restrict__ ZT, const float* __restrict__ embW,
    const float* __restrict__ embB, const float* __restrict__ g1W,
    unsigned short* __restrict__ P1TT)
{
    __shared__ float As[8][64], Cs[8][64], zs[8][64];
    __shared__ float Ws[32][68];                       // [k][d], 272B rows (16B-aligned)
    __shared__ unsigned short Dst[64][32][8];          // 32 KB stage
    int t = threadIdx.x;
    int w = t >> 6, l = t & 63;
    int lo = l & 15, q = l >> 4;
    int q8 = q << 3;
    int nb = blockIdx.x & 31, bb = blockIdx.x >> 5;
    int n0 = nb << 3, b0 = bb << 6;

    // setup
    for (int i = t; i < 512; i += 256) {
        int ni = i >> 6, d = i & 63;
        size_t eb = (size_t)(n0 + ni) * (257 * 64);
        As[ni][d] = embW[eb + d];                                   // emb_W[n,0,d]
        Cs[ni][d] = embW[eb + ((size_t)(n0 + ni + 1) << 6) + d]     // emb_W[n,n+1,d]
                  + embB[((n0 + ni) << 6) + d];
        zs[ni][d] = ZT[(size_t)(n0 + ni) * BB + b0 + d];            // d = b-local
    }
    for (int i = t; i < 2048; i += 256) {
        int d = i >> 5, k = i & 31;
        Ws[k][d] = g1W[i];                 // g1W[d*32+k], i = d*32+k
    }
    __syncthreads();

    // loop-invariant W fragments (hi/lo split)
    bf16x8 bwh[2][2], bwl[2][2];
#pragma unroll
    for (int nt = 0; nt < 2; ++nt)
#pragma unroll
        for (int kc = 0; kc < 2; ++kc) {
            float4 w0 = *(const float4*)&Ws[(nt << 4) + lo][(kc << 5) + q8];
            float4 w1 = *(const float4*)&Ws[(nt << 4) + lo][(kc << 5) + q8 + 4];
            float v[8] = {w0.x, w0.y, w0.z, w0.w, w1.x, w1.y, w1.z, w1.w};
            bf16x8 h, lq;
#pragma unroll
            for (int j = 0; j < 8; ++j) {
                unsigned short hb = f2bf(v[j]);
                h[j] = (short)hb;
                lq[j] = (short)f2bf(v[j] - bf2f(hb));
            }
            bwh[nt][kc] = h;
            bwl[nt][kc] = lq;
        }

    // main loop: one 64x32x64 GEMM per n
    for (int ni = 0; ni < 8; ++ni) {
        float zv = zs[ni][(w << 4) + lo];
        f32x4 acc0 = (f32x4)0.0f, acc1 = (f32x4)0.0f;
#pragma unroll
        for (int kc = 0; kc < 2; ++kc) {
            float4 a0 = *(const float4*)&As[ni][(kc << 5) + q8];
            float4 a1 = *(const float4*)&As[ni][(kc << 5) + q8 + 4];
            float4 c0 = *(const float4*)&Cs[ni][(kc << 5) + q8];
            float4 c1 = *(const float4*)&Cs[ni][(kc << 5) + q8 + 4];
            float e[8];
            e[0] = ftanh(fmaf(zv, a0.x, c0.x));
            e[1] = ftanh(fmaf(zv, a0.y, c0.y));
            e[2] = ftanh(fmaf(zv, a0.z, c0.z));
            e[3] = ftanh(fmaf(zv, a0.w, c0.w));
            e[4] = ftanh(fmaf(zv, a1.x, c1.x));
            e[5] = ftanh(fmaf(zv, a1.y, c1.y));
            e[6] = ftanh(fmaf(zv, a1.z, c1.z));
            e[7] = ftanh(fmaf(zv, a1.w, c1.w));
            bf16x8 ehi, elo;
#pragma unroll
            for (int j = 0; j < 8; ++j) {
                unsigned short hb = f2bf(e[j]);
                ehi[j] = (short)hb;
                elo[j] = (short)f2bf(e[j] - bf2f(hb));
            }
            acc0 = __builtin_amdgcn_mfma_f32_16x16x32_bf16(ehi, bwh[0][kc], acc0, 0, 0, 0);
            acc0 = __builtin_amdgcn_mfma_f32_16x16x32_bf16(elo, bwh[0][kc], acc0, 0, 0, 0);
            acc0 = __builtin_amdgcn_mfma_f32_16x16x32_bf16(ehi, bwl[0][kc], acc0, 0, 0, 0);
            acc1 = __builtin_amdgcn_mfma_f32_16x16x32_bf16(ehi, bwh[1][kc], acc1, 0, 0, 0);
            acc1 = __builtin_amdgcn_mfma_f32_16x16x32_bf16(elo, bwh[1][kc], acc1, 0, 0, 0);
            acc1 = __builtin_amdgcn_mfma_f32_16x16x32_bf16(ehi, bwl[1][kc], acc1, 0, 0, 0);
        }
        // stage D-frags: row b = w*16 + q*4 + r, col k = nt*16 + lo
        int bl = (w << 4) + (q << 2);
#pragma unroll
        for (int r = 0; r < 4; ++r) {
            Dst[bl + r][lo][ni]      = f2bf(acc0[r]);
            Dst[bl + r][16 + lo][ni] = f2bf(acc1[r]);
        }
    }
    __syncthreads();

    // flush: 2048 (b,k) pairs, 8 per thread, 16B each (8 n's)
    const uint4* dsp = (const uint4*)&Dst[0][0][0];
    size_t obase = ((size_t)b0 * 32) * NN + n0;    // j*NN + n0, j = b0*32 + p
#pragma unroll
    for (int i = 0; i < 8; ++i) {
        int p = (i << 8) + t;
        uint4 v = dsp[p];
        *(uint4*)&P1TT[obase + (size_t)p * NN] = v;
    }
}

// ---------------- K5: AGG1 = ADJWT @ P1TT^T via bf16 MFMA, fused epilogue -----
// C[m][j], j = b*32+k.  Block: 64 j-cols x 256 m, 4 waves (wave w: m-frags 4w..4w+3).
// No LDS: A-frag and B-frag are each one dwordx4 load (K-contiguous bf16 layouts).
__global__ __launch_bounds__(256) void k5_mfma(
    const unsigned short* __restrict__ adjwt, const unsigned short* __restrict__ p1tt,
    const float* __restrict__ g1b, const float* __restrict__ g2w,
    float* __restrict__ Q)
{
    int t = threadIdx.x;
    int w = t >> 6, l = t & 63;
    int c = l & 15, q = l >> 4;       // frag col, k-quarter
    int j0 = blockIdx.x << 6;
    int mbase = w << 6;

    f32x4 acc[4][4];                  // [mi][ji]
#pragma unroll
    for (int i = 0; i < 4; ++i)
#pragma unroll
        for (int j = 0; j < 4; ++j) acc[i][j] = (f32x4)0.0f;

    const unsigned short* ap[4];
    const unsigned short* bp[4];
#pragma unroll
    for (int mi = 0; mi < 4; ++mi)
        ap[mi] = adjwt + (size_t)(mbase + (mi << 4) + c) * NN + (q << 3);
#pragma unroll
    for (int ji = 0; ji < 4; ++ji)
        bp[ji] = p1tt + (size_t)(j0 + (ji << 4) + c) * NN + (q << 3);

#pragma unroll 2
    for (int n0 = 0; n0 < NN; n0 += 32) {
        bf16x8 af[4], bf[4];
#pragma unroll
        for (int mi = 0; mi < 4; ++mi) af[mi] = *(const bf16x8*)(ap[mi] + n0);
#pragma unroll
        for (int ji = 0; ji < 4; ++ji) bf[ji] = *(const bf16x8*)(bp[ji] + n0);
#pragma unroll
        for (int mi = 0; mi < 4; ++mi)
#pragma unroll
            for (int ji = 0; ji < 4; ++ji)
                acc[mi][ji] = __builtin_amdgcn_mfma_f32_16x16x32_bf16(
                    af[mi], bf[ji], acc[mi][ji], 0, 0, 0);
    }

    // epilogue: ji -> (b = j0/32 + (ji>>1), k = (ji&1)*16 + c)
    // D frag: lane holds rows (q*4 + r), col c. Q[b][m] = sum_k tanh(D+g1b[k])*g2w[k]
    float b1v0 = g1b[c],      g2v0 = g2w[c];
    float b1v1 = g1b[16 + c], g2v1 = g2w[16 + c];
    int bb0 = blockIdx.x << 1;
#pragma unroll
    for (int mi = 0; mi < 4; ++mi) {
#pragma unroll
        for (int bb = 0; bb < 2; ++bb) {
            float red[4];
#pragma unroll
            for (int r = 0; r < 4; ++r) {
                float s = ftanh(acc[mi][(bb << 1) + 0][r] + b1v0) * g2v0
                        + ftanh(acc[mi][(bb << 1) + 1][r] + b1v1) * g2v1;
                s += __shfl_xor(s, 1);
                s += __shfl_xor(s, 2);
                s += __shfl_xor(s, 4);
                s += __shfl_xor(s, 8);
                red[r] = s;
            }
            float* qp = &Q[(size_t)(bb0 + bb) * NN + mbase + (mi << 4) + (q << 2)];
            if (c == 0) qp[0] = red[0];
            if (c == 1) qp[1] = red[1];
            if (c == 2) qp[2] = red[2];
            if (c == 3) qp[3] = red[3];
        }
    }
}

// ---------------- K6: x_hat = Q @ ADJW + gc2_b  (1024x256 @ 256x256) ----------
__global__ __launch_bounds__(256) void k6_gc2(
    const float* __restrict__ Q, const float* __restrict__ adjw,
    const float* __restrict__ g2b, float* __restrict__ xh)
{
    __shared__ float At[64][17];
    __shared__ __align__(16) float Bt[16][64];
    int t = threadIdx.x;
    int tx = t & 15, ty = t >> 4;
    int mt = blockIdx.x & 3, bt = blockIdx.x >> 2;
    int m0 = mt << 6, b0 = bt << 6;
    float acc[4][4];
#pragma unroll
    for (int i = 0; i < 4; ++i)
#pragma unroll
        for (int j = 0; j < 4; ++j) acc[i][j] = 0.0f;

    for (int kb = 0; kb < NN; kb += 16) {
        for (int i = t; i < 1024; i += 256) {
            int kk = i & 15, c = i >> 4;
            At[c][kk] = Q[(b0 + c) * NN + kb + kk];
        }
        for (int i = t; i < 1024; i += 256) {
            int mj = i & 63, kk = i >> 6;
            Bt[kk][mj] = adjw[(kb + kk) * NN + m0 + mj];
        }
        __syncthreads();
#pragma unroll
        for (int kk = 0; kk < 16; ++kk) {
            float4 bq = *(const float4*)&Bt[kk][tx << 2];
            float am[4];
#pragma unroll
            for (int bi = 0; bi < 4; ++bi) am[bi] = At[(ty << 2) + bi][kk];
#pragma unroll
            for (int bi = 0; bi < 4; ++bi) {
                acc[bi][0] = fmaf(am[bi], bq.x, acc[bi][0]);
                acc[bi][1] = fmaf(am[bi], bq.y, acc[bi][1]);
                acc[bi][2] = fmaf(am[bi], bq.z, acc[bi][2]);
                acc[bi][3] = fmaf(am[bi], bq.w, acc[bi][3]);
            }
        }
        __syncthreads();
    }
    float bias = g2b[0];
#pragma unroll
    for (int bi = 0; bi < 4; ++bi) {
        float4 v = make_float4(acc[bi][0] + bias, acc[bi][1] + bias,
                               acc[bi][2] + bias, acc[bi][3] + bias);
        *(float4*)&xh[(b0 + (ty << 2) + bi) * NN + m0 + (tx << 2)] = v;
    }
}

extern "C" void kernel_launch(void* const* d_in, const int* in_sizes, int n_in,
                              void* d_out, int out_size, void* d_ws, size_t ws_size,
                              hipStream_t stream) {
    const float* x    = (const float*)d_in[0];
    const float* eps  = (const float*)d_in[1];
    const float* gl   = (const float*)d_in[2];
    const float* Wenc = (const float*)d_in[3];
    const float* benc = (const float*)d_in[4];
    const float* Wmu  = (const float*)d_in[5];
    const float* bmu  = (const float*)d_in[6];
    const float* Wlv  = (const float*)d_in[7];
    const float* blv  = (const float*)d_in[8];
    const float* embW = (const float*)d_in[9];
    const float* embB = (const float*)d_in[10];
    const float* g1W  = (const float*)d_in[11];
    const float* g1b  = (const float*)d_in[12];
    const float* g2W  = (const float*)d_in[13];
    const float* g2b  = (const float*)d_in[14];
    const int*   itp  = (const int*)d_in[15];

    float* ws   = (float*)d_ws;
    float* H    = ws;                                   // 65536 f
    float* ZT   = ws + 65536;                           // 262144 f
    float* ADJR = ws + 327680;                          // 65536 f
    float* DEGO = ws + 393216;                          // 256 f
    float* ADJW = ws + 393472;                          // 65536 f
    unsigned short* ADJWT = (unsigned short*)(ws + 459008);   // 65536 bf16
    unsigned short* P1TT  = (unsigned short*)(ws + 491776);   // 8388608 bf16 [j][n]
    float* Qb   = ws + 4686080;                         // 262144 f
    float* xh   = (float*)d_out;

    k1_enc  <<<256, 256, 0, stream>>>(x, Wenc, benc, H);
    k2_z    <<<256, 256, 0, stream>>>(H, Wmu, bmu, Wlv, blv, eps, ZT);
    k3a     <<<256, 256, 0, stream>>>(gl, itp, ADJR, DEGO);
    k3b     <<<256, 256, 0, stream>>>(ADJR, DEGO, ADJW, ADJWT);
    k4_mfma <<<512, 256, 0, stream>>>(ZT, embW, embB, g1W, P1TT);
    k5_mfma <<<512, 256, 0, stream>>>(ADJWT, P1TT, g1b, g2W, Qb);
    k6_gc2  <<<64,  256, 0, stream>>>(Qb, ADJW, g2b, xh);
}

// Round 7
// 180.526 us; speedup vs baseline: 1.4481x; 1.1354x over previous
//
#include <hip/hip_runtime.h>
#include <hip/hip_bf16.h>
#include <math.h>

#define NN 256
#define BB 1024
#define DD 64

typedef short bf16x8 __attribute__((ext_vector_type(8)));
typedef float f32x4 __attribute__((ext_vector_type(4)));

__device__ __forceinline__ float ftanh(float x) {
    float e = __expf(2.0f * x);
    return 1.0f - 2.0f * __builtin_amdgcn_rcpf(e + 1.0f);
}

__device__ __forceinline__ unsigned short f2bf(float v) {
    __hip_bfloat16 h = __float2bfloat16(v);
    return *reinterpret_cast<unsigned short*>(&h);
}

__device__ __forceinline__ float bf2f(unsigned short u) {
    union { unsigned int i; float f; } c;
    c.i = ((unsigned int)u) << 16;
    return c.f;
}

// ---------------- K12: fused encoder: H = relu(xW+b) in LDS; z -> ZT[n][b] ----
// grid 256 (4 b's per block), 256 thr
__global__ __launch_bounds__(256) void k12(
    const float* __restrict__ x, const float* __restrict__ Wenc,
    const float* __restrict__ benc, const float* __restrict__ Wmu,
    const float* __restrict__ bmu, const float* __restrict__ Wlv,
    const float* __restrict__ blv, const float* __restrict__ eps,
    float* __restrict__ ZT)
{
    __shared__ float Hs[4][DD];
    int t = threadIdx.x;
    int b0 = blockIdx.x << 2;
    {   // phase 1: H tile (4 x 64)
        int d = t & 63, bl = t >> 6;
        const float* xr = x + (b0 + bl) * NN;
        float acc = benc[d];
        for (int n = 0; n < NN; n += 4) {
            float4 xv = *(const float4*)&xr[n];
            acc = fmaf(xv.x, Wenc[(n + 0) * DD + d], acc);
            acc = fmaf(xv.y, Wenc[(n + 1) * DD + d], acc);
            acc = fmaf(xv.z, Wenc[(n + 2) * DD + d], acc);
            acc = fmaf(xv.w, Wenc[(n + 3) * DD + d], acc);
        }
        Hs[bl][d] = fmaxf(acc, 0.0f);
    }
    __syncthreads();
    {   // phase 2: mu/logvar/z for n = t, 4 b's
        int n = t;
        float mu[4], lv[4];
        float bm = bmu[n], bl_ = blv[n];
#pragma unroll
        for (int i = 0; i < 4; ++i) { mu[i] = bm; lv[i] = bl_; }
        for (int d = 0; d < DD; ++d) {
            float wm = Wmu[d * NN + n];
            float wl = Wlv[d * NN + n];
#pragma unroll
            for (int i = 0; i < 4; ++i) {
                float h = Hs[i][d];
                mu[i] = fmaf(h, wm, mu[i]);
                lv[i] = fmaf(h, wl, lv[i]);
            }
        }
#pragma unroll
        for (int i = 0; i < 4; ++i) {
            int b = b0 + i;
            ZT[n * BB + b] = fmaf(eps[b * NN + n], expf(0.5f * lv[i]), mu[i]);
        }
    }
}

// ---------------- K3a: adj rows (sigmoid + self-loop + threshold), deg_out ----
__global__ __launch_bounds__(256) void k3a(
    const float* __restrict__ gl, const int* __restrict__ itp,
    float* __restrict__ adj, float* __restrict__ dego)
{
    int nrow = blockIdx.x, m = threadIdx.x;
    float v = gl[nrow * NN + m];
    float a = (nrow == m) ? 1.0f : 1.0f / (1.0f + expf(-v));
    if (itp[0] > 50 && !(a > 0.1f)) a = 0.0f;
    adj[nrow * NN + m] = a;
    unsigned long long ball = __ballot(a != 0.0f);
    __shared__ int cnt_s[4];
    if ((m & 63) == 0) cnt_s[m >> 6] = __popcll(ball);
    __syncthreads();
    if (m == 0) dego[nrow] = (float)(cnt_s[0] + cnt_s[1] + cnt_s[2] + cnt_s[3]);
}

// ---------------- K3b: deg_in + ADJW[n][m] f32 + ADJWT[m][n] bf16 -------------
__global__ __launch_bounds__(256) void k3b(
    const float* __restrict__ adj, const float* __restrict__ dego,
    float* __restrict__ adjw, unsigned short* __restrict__ adjwt)
{
    int m = blockIdx.x, nrow = threadIdx.x;
    float a = adj[nrow * NN + m];
    unsigned long long ball = __ballot(a != 0.0f);
    __shared__ int cnt_s[4];
    __shared__ float din_s;
    if ((nrow & 63) == 0) cnt_s[nrow >> 6] = __popcll(ball);
    __syncthreads();
    if (nrow == 0) din_s = (float)(cnt_s[0] + cnt_s[1] + cnt_s[2] + cnt_s[3]);
    __syncthreads();
    float w = a * (1.0f / sqrtf(dego[nrow])) * (1.0f / sqrtf(din_s));
    adjw[nrow * NN + m] = w;
    adjwt[m * NN + nrow] = f2bf(w);
}

// ---------------- K4: P1TT[j][n] = bf16( tanh(z*A+C) @ gc1_W ) via MFMA -------
// v2: 4 n x 64 b per block, grid 1024 = 64 nb x 16 bb; LDS ~28KB -> 4 blk/CU.
// Split-bf16 (hi/lo) keeps f32-level accuracy.
__global__ __launch_bounds__(256) void k4_mfma(
    const float* __restrict__ ZT, const float* __restrict__ embW,
    const float* __restrict__ embB, const float* __restrict__ g1W,
    unsigned short* __restrict__ P1TT)
{
    __shared__ float As[4][64], Cs[4][64], zs[4][64];
    __shared__ float Ws[32][68];
    __shared__ __align__(16) unsigned short Dst[64][32][4];   // 16 KB
    int t = threadIdx.x;
    int w = t >> 6, l = t & 63;
    int lo = l & 15, q = l >> 4;
    int q8 = q << 3;
    int nb = blockIdx.x & 63, bb = blockIdx.x >> 6;
    int n0 = nb << 2, b0 = bb << 6;

    {   // setup: 4n x 64 = 256 elements, one per thread
        int ni = t >> 6, d = t & 63;
        size_t eb = (size_t)(n0 + ni) * (257 * 64);
        As[ni][d] = embW[eb + d];
        Cs[ni][d] = embW[eb + ((size_t)(n0 + ni + 1) << 6) + d]
                  + embB[((n0 + ni) << 6) + d];
        zs[ni][d] = ZT[(size_t)(n0 + ni) * BB + b0 + d];
    }
    for (int i = t; i < 2048; i += 256) {
        int d = i >> 5, k = i & 31;
        Ws[k][d] = g1W[i];
    }
    __syncthreads();

    bf16x8 bwh[2][2], bwl[2][2];
#pragma unroll
    for (int nt = 0; nt < 2; ++nt)
#pragma unroll
        for (int kc = 0; kc < 2; ++kc) {
            float4 w0 = *(const float4*)&Ws[(nt << 4) + lo][(kc << 5) + q8];
            float4 w1 = *(const float4*)&Ws[(nt << 4) + lo][(kc << 5) + q8 + 4];
            float v[8] = {w0.x, w0.y, w0.z, w0.w, w1.x, w1.y, w1.z, w1.w};
            bf16x8 h, lq;
#pragma unroll
            for (int j = 0; j < 8; ++j) {
                unsigned short hb = f2bf(v[j]);
                h[j] = (short)hb;
                lq[j] = (short)f2bf(v[j] - bf2f(hb));
            }
            bwh[nt][kc] = h;
            bwl[nt][kc] = lq;
        }

#pragma unroll
    for (int ni = 0; ni < 4; ++ni) {
        float zv = zs[ni][(w << 4) + lo];
        f32x4 acc0 = (f32x4)0.0f, acc1 = (f32x4)0.0f;
#pragma unroll
        for (int kc = 0; kc < 2; ++kc) {
            float4 a0 = *(const float4*)&As[ni][(kc << 5) + q8];
            float4 a1 = *(const float4*)&As[ni][(kc << 5) + q8 + 4];
            float4 c0 = *(const float4*)&Cs[ni][(kc << 5) + q8];
            float4 c1 = *(const float4*)&Cs[ni][(kc << 5) + q8 + 4];
            float e[8];
            e[0] = ftanh(fmaf(zv, a0.x, c0.x));
            e[1] = ftanh(fmaf(zv, a0.y, c0.y));
            e[2] = ftanh(fmaf(zv, a0.z, c0.z));
            e[3] = ftanh(fmaf(zv, a0.w, c0.w));
            e[4] = ftanh(fmaf(zv, a1.x, c1.x));
            e[5] = ftanh(fmaf(zv, a1.y, c1.y));
            e[6] = ftanh(fmaf(zv, a1.z, c1.z));
            e[7] = ftanh(fmaf(zv, a1.w, c1.w));
            bf16x8 ehi, elo;
#pragma unroll
            for (int j = 0; j < 8; ++j) {
                unsigned short hb = f2bf(e[j]);
                ehi[j] = (short)hb;
                elo[j] = (short)f2bf(e[j] - bf2f(hb));
            }
            acc0 = __builtin_amdgcn_mfma_f32_16x16x32_bf16(ehi, bwh[0][kc], acc0, 0, 0, 0);
            acc0 = __builtin_amdgcn_mfma_f32_16x16x32_bf16(elo, bwh[0][kc], acc0, 0, 0, 0);
            acc0 = __builtin_amdgcn_mfma_f32_16x16x32_bf16(ehi, bwl[0][kc], acc0, 0, 0, 0);
            acc1 = __builtin_amdgcn_mfma_f32_16x16x32_bf16(ehi, bwh[1][kc], acc1, 0, 0, 0);
            acc1 = __builtin_amdgcn_mfma_f32_16x16x32_bf16(elo, bwh[1][kc], acc1, 0, 0, 0);
            acc1 = __builtin_amdgcn_mfma_f32_16x16x32_bf16(ehi, bwl[1][kc], acc1, 0, 0, 0);
        }
        int bl = (w << 4) + (q << 2);
#pragma unroll
        for (int r = 0; r < 4; ++r) {
            Dst[bl + r][lo][ni]      = f2bf(acc0[r]);
            Dst[bl + r][16 + lo][ni] = f2bf(acc1[r]);
        }
    }
    __syncthreads();

    // flush: 2048 (b,k) pairs x 8B (4 n's)
    const uint2* dsp = (const uint2*)&Dst[0][0][0];
    size_t obase = ((size_t)b0 * 32) * NN + n0;
#pragma unroll
    for (int i = 0; i < 8; ++i) {
        int p = (i << 8) + t;
        uint2 v = dsp[p];
        *(uint2*)&P1TT[obase + (size_t)p * NN] = v;
    }
}

// ---------------- K5: AGG1 = ADJWT @ P1TT^T (bf16 MFMA), fused tanh+gc2 -------
// v2: block = 64 j x 128 m (wave w: 2 m-frags), grid 1024 = 512 jt x 2 mh.
__global__ __launch_bounds__(256) void k5_mfma(
    const unsigned short* __restrict__ adjwt, const unsigned short* __restrict__ p1tt,
    const float* __restrict__ g1b, const float* __restrict__ g2w,
    float* __restrict__ Q)
{
    int t = threadIdx.x;
    int w = t >> 6, l = t & 63;
    int c = l & 15, q = l >> 4;
    int jt = blockIdx.x >> 1, mh = blockIdx.x & 1;
    int j0 = jt << 6;
    int mbase = (mh << 7) + (w << 5);

    f32x4 acc[2][4];
#pragma unroll
    for (int i = 0; i < 2; ++i)
#pragma unroll
        for (int j = 0; j < 4; ++j) acc[i][j] = (f32x4)0.0f;

    const unsigned short* ap[2];
    const unsigned short* bp[4];
#pragma unroll
    for (int mi = 0; mi < 2; ++mi)
        ap[mi] = adjwt + (size_t)(mbase + (mi << 4) + c) * NN + (q << 3);
#pragma unroll
    for (int ji = 0; ji < 4; ++ji)
        bp[ji] = p1tt + (size_t)(j0 + (ji << 4) + c) * NN + (q << 3);

#pragma unroll 2
    for (int n0 = 0; n0 < NN; n0 += 32) {
        bf16x8 af[2], bf[4];
#pragma unroll
        for (int mi = 0; mi < 2; ++mi) af[mi] = *(const bf16x8*)(ap[mi] + n0);
#pragma unroll
        for (int ji = 0; ji < 4; ++ji) bf[ji] = *(const bf16x8*)(bp[ji] + n0);
#pragma unroll
        for (int mi = 0; mi < 2; ++mi)
#pragma unroll
            for (int ji = 0; ji < 4; ++ji)
                acc[mi][ji] = __builtin_amdgcn_mfma_f32_16x16x32_bf16(
                    af[mi], bf[ji], acc[mi][ji], 0, 0, 0);
    }

    float b1v0 = g1b[c],      g2v0 = g2w[c];
    float b1v1 = g1b[16 + c], g2v1 = g2w[16 + c];
    int bb0 = jt << 1;
#pragma unroll
    for (int mi = 0; mi < 2; ++mi) {
#pragma unroll
        for (int bb = 0; bb < 2; ++bb) {
            float red[4];
#pragma unroll
            for (int r = 0; r < 4; ++r) {
                float s = ftanh(acc[mi][(bb << 1) + 0][r] + b1v0) * g2v0
                        + ftanh(acc[mi][(bb << 1) + 1][r] + b1v1) * g2v1;
                s += __shfl_xor(s, 1);
                s += __shfl_xor(s, 2);
                s += __shfl_xor(s, 4);
                s += __shfl_xor(s, 8);
                red[r] = s;
            }
            float* qp = &Q[(size_t)(bb0 + bb) * NN + mbase + (mi << 4) + (q << 2)];
            if (c == 0) qp[0] = red[0];
            if (c == 1) qp[1] = red[1];
            if (c == 2) qp[2] = red[2];
            if (c == 3) qp[3] = red[3];
        }
    }
}

// ---------------- K6: x_hat = Q @ ADJW + gc2_b ; 32x32 tiles, grid 256 --------
__global__ __launch_bounds__(256) void k6_gc2(
    const float* __restrict__ Q, const float* __restrict__ adjw,
    const float* __restrict__ g2b, float* __restrict__ xh)
{
    __shared__ float At[32][33];     // [b_local][kk]
    __shared__ float Bt[32][33];     // [kk][m_local]
    int t = threadIdx.x;
    int tx = t & 15, ty = t >> 4;
    int mt = blockIdx.x & 7, bt = blockIdx.x >> 3;
    int m0 = mt << 5, b0 = bt << 5;
    float acc[2][2] = {{0.0f, 0.0f}, {0.0f, 0.0f}};

    for (int kb = 0; kb < NN; kb += 32) {
        for (int i = t; i < 1024; i += 256) {
            int r = i >> 5, cc = i & 31;
            At[r][cc] = Q[(b0 + r) * NN + kb + cc];
            Bt[r][cc] = adjw[(kb + r) * NN + m0 + cc];
        }
        __syncthreads();
#pragma unroll 8
        for (int kk = 0; kk < 32; ++kk) {
            float bv0 = Bt[kk][tx << 1], bv1 = Bt[kk][(tx << 1) + 1];
            float a0 = At[ty << 1][kk], a1 = At[(ty << 1) + 1][kk];
            acc[0][0] = fmaf(a0, bv0, acc[0][0]);
            acc[0][1] = fmaf(a0, bv1, acc[0][1]);
            acc[1][0] = fmaf(a1, bv0, acc[1][0]);
            acc[1][1] = fmaf(a1, bv1, acc[1][1]);
        }
        __syncthreads();
    }
    float bias = g2b[0];
#pragma unroll
    for (int i = 0; i < 2; ++i) {
        float2 v = make_float2(acc[i][0] + bias, acc[i][1] + bias);
        *(float2*)&xh[(b0 + (ty << 1) + i) * NN + m0 + (tx << 1)] = v;
    }
}

extern "C" void kernel_launch(void* const* d_in, const int* in_sizes, int n_in,
                              void* d_out, int out_size, void* d_ws, size_t ws_size,
                              hipStream_t stream) {
    const float* x    = (const float*)d_in[0];
    const float* eps  = (const float*)d_in[1];
    const float* gl   = (const float*)d_in[2];
    const float* Wenc = (const float*)d_in[3];
    const float* benc = (const float*)d_in[4];
    const float* Wmu  = (const float*)d_in[5];
    const float* bmu  = (const float*)d_in[6];
    const float* Wlv  = (const float*)d_in[7];
    const float* blv  = (const float*)d_in[8];
    const float* embW = (const float*)d_in[9];
    const float* embB = (const float*)d_in[10];
    const float* g1W  = (const float*)d_in[11];
    const float* g1b  = (const float*)d_in[12];
    const float* g2W  = (const float*)d_in[13];
    const float* g2b  = (const float*)d_in[14];
    const int*   itp  = (const int*)d_in[15];

    float* ws   = (float*)d_ws;
    float* ZT   = ws + 65536;                           // 262144 f
    float* ADJR = ws + 327680;                          // 65536 f
    float* DEGO = ws + 393216;                          // 256 f
    float* ADJW = ws + 393472;                          // 65536 f
    unsigned short* ADJWT = (unsigned short*)(ws + 459008);   // 65536 bf16
    unsigned short* P1TT  = (unsigned short*)(ws + 491776);   // 8388608 bf16 [j][n]
    float* Qb   = ws + 4686080;                         // 262144 f
    float* xh   = (float*)d_out;

    k12     <<<256,  256, 0, stream>>>(x, Wenc, benc, Wmu, bmu, Wlv, blv, eps, ZT);
    k3a     <<<256,  256, 0, stream>>>(gl, itp, ADJR, DEGO);
    k3b     <<<256,  256, 0, stream>>>(ADJR, DEGO, ADJW, ADJWT);
    k4_mfma <<<1024, 256, 0, stream>>>(ZT, embW, embB, g1W, P1TT);
    k5_mfma <<<1024, 256, 0, stream>>>(ADJWT, P1TT, g1b, g2W, Qb);
    k6_gc2  <<<256,  256, 0, stream>>>(Qb, ADJW, g2b, xh);
}

// Round 12
// 178.427 us; speedup vs baseline: 1.4652x; 1.0118x over previous
//
#include <hip/hip_runtime.h>
#include <hip/hip_bf16.h>
#include <math.h>

#define NN 256
#define BB 1024
#define DD 64

typedef short bf16x8 __attribute__((ext_vector_type(8)));
typedef float f32x4 __attribute__((ext_vector_type(4)));

__device__ __forceinline__ float ftanh(float x) {
    float e = __expf(2.0f * x);
    return 1.0f - 2.0f * __builtin_amdgcn_rcpf(e + 1.0f);
}

__device__ __forceinline__ unsigned short f2bf(float v) {
    __hip_bfloat16 h = __float2bfloat16(v);
    return *reinterpret_cast<unsigned short*>(&h);
}

__device__ __forceinline__ float bf2f(unsigned short u) {
    union { unsigned int i; float f; } c;
    c.i = ((unsigned int)u) << 16;
    return c.f;
}

// ============ kA: blocks 0-255: encoder+z (k12). blocks 256-511: k3a. ========
__global__ __launch_bounds__(256) void kA(
    const float* __restrict__ x, const float* __restrict__ eps,
    const float* __restrict__ gl, const float* __restrict__ Wenc,
    const float* __restrict__ benc, const float* __restrict__ Wmu,
    const float* __restrict__ bmu, const float* __restrict__ Wlv,
    const float* __restrict__ blv, const int* __restrict__ itp,
    float* __restrict__ ZT, float* __restrict__ ADJ, float* __restrict__ DEGO)
{
    __shared__ float Hs[4][DD];
    __shared__ int cnt_s[4];
    int t = threadIdx.x;
    int bid = blockIdx.x;

    if (bid < 256) {
        int b0 = bid << 2;
        {
            int d = t & 63, bl = t >> 6;
            const float* xr = x + (b0 + bl) * NN;
            float acc = benc[d];
            for (int n = 0; n < NN; n += 4) {
                float4 xv = *(const float4*)&xr[n];
                acc = fmaf(xv.x, Wenc[(n + 0) * DD + d], acc);
                acc = fmaf(xv.y, Wenc[(n + 1) * DD + d], acc);
                acc = fmaf(xv.z, Wenc[(n + 2) * DD + d], acc);
                acc = fmaf(xv.w, Wenc[(n + 3) * DD + d], acc);
            }
            Hs[bl][d] = fmaxf(acc, 0.0f);
        }
        __syncthreads();
        {
            int n = t;
            float mu[4], lv[4];
            float bm = bmu[n], bl_ = blv[n];
#pragma unroll
            for (int i = 0; i < 4; ++i) { mu[i] = bm; lv[i] = bl_; }
            for (int d = 0; d < DD; ++d) {
                float wm = Wmu[d * NN + n];
                float wl = Wlv[d * NN + n];
#pragma unroll
                for (int i = 0; i < 4; ++i) {
                    float h = Hs[i][d];
                    mu[i] = fmaf(h, wm, mu[i]);
                    lv[i] = fmaf(h, wl, lv[i]);
                }
            }
#pragma unroll
            for (int i = 0; i < 4; ++i) {
                int b = b0 + i;
                ZT[n * BB + b] = fmaf(eps[b * NN + n], expf(0.5f * lv[i]), mu[i]);
            }
        }
    } else {
        int nrow = bid - 256, m = t;
        float v = gl[nrow * NN + m];
        float a = (nrow == m) ? 1.0f : 1.0f / (1.0f + expf(-v));
        if (itp[0] > 50 && !(a > 0.1f)) a = 0.0f;
        ADJ[nrow * NN + m] = a;
        unsigned long long ball = __ballot(a != 0.0f);
        if ((m & 63) == 0) cnt_s[m >> 6] = __popcll(ball);
        __syncthreads();
        if (m == 0) DEGO[nrow] = (float)(cnt_s[0] + cnt_s[1] + cnt_s[2] + cnt_s[3]);
    }
}

// ============ kB: blocks 0-255 prepend k3b (1 col); all blocks: 2 k4 tiles ====
__global__ __launch_bounds__(256) void kB(
    const float* __restrict__ ZT, const float* __restrict__ embW,
    const float* __restrict__ embB, const float* __restrict__ g1W,
    const float* __restrict__ ADJ, const float* __restrict__ DEGO,
    float* __restrict__ ADJW, unsigned short* __restrict__ ADJWT,
    unsigned short* __restrict__ P1TT)
{
    __shared__ __align__(16) unsigned char smem[28160];
    int t = threadIdx.x;
    int bid = blockIdx.x;

    if (bid < 256) {
        // --- k3b: column bid -> ADJW f32 [n][m], ADJWT bf16 [m][n] ---
        int m = bid;
        int* cnt_s = (int*)smem;
        float* din_s = (float*)(smem + 16);
        float a = ADJ[t * NN + m];
        unsigned long long ball = __ballot(a != 0.0f);
        if ((t & 63) == 0) cnt_s[t >> 6] = __popcll(ball);
        __syncthreads();
        if (t == 0) din_s[0] = (float)(cnt_s[0] + cnt_s[1] + cnt_s[2] + cnt_s[3]);
        __syncthreads();
        float wv = a * (1.0f / sqrtf(DEGO[t])) * (1.0f / sqrtf(din_s[0]));
        ADJW[t * NN + m] = wv;
        ADJWT[m * NN + t] = f2bf(wv);
    }

    // --- k4: P1TT[j][n] = bf16( tanh(z*A+C) @ gc1_W ), 2 tiles/block ---
    {
        float (*As)[64] = (float(*)[64])(smem);
        float (*Cs)[64] = (float(*)[64])(smem + 1024);
        float (*zsm)[64] = (float(*)[64])(smem + 2048);
        float (*Ws)[68] = (float(*)[68])(smem + 3072);
        unsigned short (*Dst)[32][4] = (unsigned short(*)[32][4])(smem + 11776);
        int w = t >> 6, l = t & 63;
        int lo = l & 15, q = l >> 4;
        int q8 = q << 3;

        for (int i = t; i < 2048; i += 256) {
            int d = i >> 5, k = i & 31;
            Ws[k][d] = g1W[i];
        }
        __syncthreads();

        bf16x8 bwh[2][2], bwl[2][2];
#pragma unroll
        for (int nt = 0; nt < 2; ++nt)
#pragma unroll
            for (int kc = 0; kc < 2; ++kc) {
                float4 w0 = *(const float4*)&Ws[(nt << 4) + lo][(kc << 5) + q8];
                float4 w1 = *(const float4*)&Ws[(nt << 4) + lo][(kc << 5) + q8 + 4];
                float v[8] = {w0.x, w0.y, w0.z, w0.w, w1.x, w1.y, w1.z, w1.w};
                bf16x8 h, lq;
#pragma unroll
                for (int j = 0; j < 8; ++j) {
                    unsigned short hb = f2bf(v[j]);
                    h[j] = (short)hb;
                    lq[j] = (short)f2bf(v[j] - bf2f(hb));
                }
                bwh[nt][kc] = h;
                bwl[nt][kc] = lq;
            }

        for (int it = 0; it < 2; ++it) {
            int tile = (bid << 1) | it;
            int nb = tile & 63, bb2 = tile >> 6;
            int n0 = nb << 2, b0 = bb2 << 6;
            __syncthreads();
            {
                int ni = t >> 6, d = t & 63;
                size_t eb = (size_t)(n0 + ni) * (257 * 64);
                As[ni][d] = embW[eb + d];
                Cs[ni][d] = embW[eb + ((size_t)(n0 + ni + 1) << 6) + d]
                          + embB[((n0 + ni) << 6) + d];
                zsm[ni][d] = ZT[(size_t)(n0 + ni) * BB + b0 + d];
            }
            __syncthreads();
#pragma unroll
            for (int ni = 0; ni < 4; ++ni) {
                float zv = zsm[ni][(w << 4) + lo];
                f32x4 acc0 = (f32x4)0.0f, acc1 = (f32x4)0.0f;
#pragma unroll
                for (int kc = 0; kc < 2; ++kc) {
                    float4 a0 = *(const float4*)&As[ni][(kc << 5) + q8];
                    float4 a1 = *(const float4*)&As[ni][(kc << 5) + q8 + 4];
                    float4 c0 = *(const float4*)&Cs[ni][(kc << 5) + q8];
                    float4 c1 = *(const float4*)&Cs[ni][(kc << 5) + q8 + 4];
                    float e[8];
                    e[0] = ftanh(fmaf(zv, a0.x, c0.x));
                    e[1] = ftanh(fmaf(zv, a0.y, c0.y));
                    e[2] = ftanh(fmaf(zv, a0.z, c0.z));
                    e[3] = ftanh(fmaf(zv, a0.w, c0.w));
                    e[4] = ftanh(fmaf(zv, a1.x, c1.x));
                    e[5] = ftanh(fmaf(zv, a1.y, c1.y));
                    e[6] = ftanh(fmaf(zv, a1.z, c1.z));
                    e[7] = ftanh(fmaf(zv, a1.w, c1.w));
                    bf16x8 ehi, elo;
#pragma unroll
                    for (int j = 0; j < 8; ++j) {
                        unsigned short hb = f2bf(e[j]);
                        ehi[j] = (short)hb;
                        elo[j] = (short)f2bf(e[j] - bf2f(hb));
                    }
                    acc0 = __builtin_amdgcn_mfma_f32_16x16x32_bf16(ehi, bwh[0][kc], acc0, 0, 0, 0);
                    acc0 = __builtin_amdgcn_mfma_f32_16x16x32_bf16(elo, bwh[0][kc], acc0, 0, 0, 0);
                    acc0 = __builtin_amdgcn_mfma_f32_16x16x32_bf16(ehi, bwl[0][kc], acc0, 0, 0, 0);
                    acc1 = __builtin_amdgcn_mfma_f32_16x16x32_bf16(ehi, bwh[1][kc], acc1, 0, 0, 0);
                    acc1 = __builtin_amdgcn_mfma_f32_16x16x32_bf16(elo, bwh[1][kc], acc1, 0, 0, 0);
                    acc1 = __builtin_amdgcn_mfma_f32_16x16x32_bf16(ehi, bwl[1][kc], acc1, 0, 0, 0);
                }
                int bl = (w << 4) + (q << 2);
#pragma unroll
                for (int r = 0; r < 4; ++r) {
                    Dst[bl + r][lo][ni]      = f2bf(acc0[r]);
                    Dst[bl + r][16 + lo][ni] = f2bf(acc1[r]);
                }
            }
            __syncthreads();
            const uint2* dsp = (const uint2*)&Dst[0][0][0];
            size_t obase = ((size_t)b0 * 32) * NN + n0;
#pragma unroll
            for (int i = 0; i < 8; ++i) {
                int p = (i << 8) + t;
                uint2 v = dsp[p];
                *(uint2*)&P1TT[obase + (size_t)p * NN] = v;
            }
        }
    }
}

// ============ kC: k5 = ADJWT @ P1TT^T (bf16 MFMA), fused tanh+gc2 ============
// grid 1024 = 512 jt x 2 mh (R7-measured geometry)
__global__ __launch_bounds__(256) void kC(
    const unsigned short* __restrict__ adjwt, const unsigned short* __restrict__ p1tt,
    const float* __restrict__ g1b, const float* __restrict__ g2w,
    float* __restrict__ Q)
{
    int t = threadIdx.x;
    int w = t >> 6, l = t & 63;
    int c = l & 15, q = l >> 4;
    int jt = blockIdx.x >> 1, mh = blockIdx.x & 1;
    int j0 = jt << 6;
    int mbase = (mh << 7) + (w << 5);

    f32x4 acc[2][4];
#pragma unroll
    for (int i = 0; i < 2; ++i)
#pragma unroll
        for (int j = 0; j < 4; ++j) acc[i][j] = (f32x4)0.0f;

    const unsigned short* ap[2];
    const unsigned short* bp[4];
#pragma unroll
    for (int mi = 0; mi < 2; ++mi)
        ap[mi] = adjwt + (size_t)(mbase + (mi << 4) + c) * NN + (q << 3);
#pragma unroll
    for (int ji = 0; ji < 4; ++ji)
        bp[ji] = p1tt + (size_t)(j0 + (ji << 4) + c) * NN + (q << 3);

#pragma unroll 2
    for (int n0 = 0; n0 < NN; n0 += 32) {
        bf16x8 af[2], bf[4];
#pragma unroll
        for (int mi = 0; mi < 2; ++mi) af[mi] = *(const bf16x8*)(ap[mi] + n0);
#pragma unroll
        for (int ji = 0; ji < 4; ++ji) bf[ji] = *(const bf16x8*)(bp[ji] + n0);
#pragma unroll
        for (int mi = 0; mi < 2; ++mi)
#pragma unroll
            for (int ji = 0; ji < 4; ++ji)
                acc[mi][ji] = __builtin_amdgcn_mfma_f32_16x16x32_bf16(
                    af[mi], bf[ji], acc[mi][ji], 0, 0, 0);
    }

    float b1v0 = g1b[c],      g2v0 = g2w[c];
    float b1v1 = g1b[16 + c], g2v1 = g2w[16 + c];
    int bb0 = jt << 1;
#pragma unroll
    for (int mi = 0; mi < 2; ++mi) {
#pragma unroll
        for (int bb = 0; bb < 2; ++bb) {
            float red[4];
#pragma unroll
            for (int r = 0; r < 4; ++r) {
                float s = ftanh(acc[mi][(bb << 1) + 0][r] + b1v0) * g2v0
                        + ftanh(acc[mi][(bb << 1) + 1][r] + b1v1) * g2v1;
                s += __shfl_xor(s, 1);
                s += __shfl_xor(s, 2);
                s += __shfl_xor(s, 4);
                s += __shfl_xor(s, 8);
                red[r] = s;
            }
            float* qp = &Q[(size_t)(bb0 + bb) * NN + mbase + (mi << 4) + (q << 2)];
            if (c == 0) qp[0] = red[0];
            if (c == 1) qp[1] = red[1];
            if (c == 2) qp[2] = red[2];
            if (c == 3) qp[3] = red[3];
        }
    }
}

// ============ kD: k6 = Q @ ADJW + gc2_b ; 32x32 tiles, grid 256 ==============
__global__ __launch_bounds__(256) void kD(
    const float* __restrict__ Q, const float* __restrict__ adjw,
    const float* __restrict__ g2b, float* __restrict__ xh)
{
    __shared__ float At[32][33];
    __shared__ float Bt[32][33];
    int t = threadIdx.x;
    int tx = t & 15, ty = t >> 4;
    int mt = blockIdx.x & 7, bt = blockIdx.x >> 3;
    int m0 = mt << 5, b0 = bt << 5;
    float acc[2][2] = {{0.0f, 0.0f}, {0.0f, 0.0f}};

    for (int kb = 0; kb < NN; kb += 32) {
        for (int i = t; i < 1024; i += 256) {
            int r = i >> 5, cc = i & 31;
            At[r][cc] = Q[(b0 + r) * NN + kb + cc];
            Bt[r][cc] = adjw[(kb + r) * NN + m0 + cc];
        }
        __syncthreads();
#pragma unroll 8
        for (int kk = 0; kk < 32; ++kk) {
            float bv0 = Bt[kk][tx << 1], bv1 = Bt[kk][(tx << 1) + 1];
            float a0 = At[ty << 1][kk], a1 = At[(ty << 1) + 1][kk];
            acc[0][0] = fmaf(a0, bv0, acc[0][0]);
            acc[0][1] = fmaf(a0, bv1, acc[0][1]);
            acc[1][0] = fmaf(a1, bv0, acc[1][0]);
            acc[1][1] = fmaf(a1, bv1, acc[1][1]);
        }
        __syncthreads();
    }
    float bias = g2b[0];
#pragma unroll
    for (int i = 0; i < 2; ++i) {
        float2 v = make_float2(acc[i][0] + bias, acc[i][1] + bias);
        *(float2*)&xh[(b0 + (ty << 1) + i) * NN + m0 + (tx << 1)] = v;
    }
}

extern "C" void kernel_launch(void* const* d_in, const int* in_sizes, int n_in,
                              void* d_out, int out_size, void* d_ws, size_t ws_size,
                              hipStream_t stream) {
    const float* x    = (const float*)d_in[0];
    const float* eps  = (const float*)d_in[1];
    const float* gl   = (const float*)d_in[2];
    const float* Wenc = (const float*)d_in[3];
    const float* benc = (const float*)d_in[4];
    const float* Wmu  = (const float*)d_in[5];
    const float* bmu  = (const float*)d_in[6];
    const float* Wlv  = (const float*)d_in[7];
    const float* blv  = (const float*)d_in[8];
    const float* embW = (const float*)d_in[9];
    const float* embB = (const float*)d_in[10];
    const float* g1W  = (const float*)d_in[11];
    const float* g1b  = (const float*)d_in[12];
    const float* g2W  = (const float*)d_in[13];
    const float* g2b  = (const float*)d_in[14];
    const int*   itp  = (const int*)d_in[15];

    float* ws   = (float*)d_ws;
    float* ZT   = ws + 65536;
    float* ADJ  = ws + 327680;
    float* DEGO = ws + 393216;
    float* ADJW = ws + 393472;
    unsigned short* ADJWT = (unsigned short*)(ws + 459008);
    unsigned short* P1TT  = (unsigned short*)(ws + 491776);
    float* Qb   = ws + 4686080;
    float* xh   = (float*)d_out;

    kA<<<512,  256, 0, stream>>>(x, eps, gl, Wenc, benc, Wmu, bmu, Wlv, blv,
                                 itp, ZT, ADJ, DEGO);
    kB<<<512,  256, 0, stream>>>(ZT, embW, embB, g1W, ADJ, DEGO, ADJW, ADJWT, P1TT);
    kC<<<1024, 256, 0, stream>>>(ADJWT, P1TT, g1b, g2W, Qb);
    kD<<<256,  256, 0, stream>>>(Qb, ADJW, g2b, xh);
}

// Round 14
// 170.627 us; speedup vs baseline: 1.5322x; 1.0457x over previous
//
#include <hip/hip_runtime.h>
#include <hip/hip_bf16.h>
#include <math.h>

#define NN 256
#define BB 1024
#define DD 64

typedef short bf16x8 __attribute__((ext_vector_type(8)));
typedef float f32x4 __attribute__((ext_vector_type(4)));

__device__ __forceinline__ float ftanh(float x) {
    float e = __expf(2.0f * x);
    return 1.0f - 2.0f * __builtin_amdgcn_rcpf(e + 1.0f);
}

__device__ __forceinline__ unsigned short f2bf(float v) {
    __hip_bfloat16 h = __float2bfloat16(v);
    return *reinterpret_cast<unsigned short*>(&h);
}

__device__ __forceinline__ float bf2f(unsigned short u) {
    union { unsigned int i; float f; } c;
    c.i = ((unsigned int)u) << 16;
    return c.f;
}

// ============ kA: blocks 0-255: encoder+z (k12). blocks 256-511: k3a. ========
__global__ __launch_bounds__(256) void kA(
    const float* __restrict__ x, const float* __restrict__ eps,
    const float* __restrict__ gl, const float* __restrict__ Wenc,
    const float* __restrict__ benc, const float* __restrict__ Wmu,
    const float* __restrict__ bmu, const float* __restrict__ Wlv,
    const float* __restrict__ blv, const int* __restrict__ itp,
    float* __restrict__ ZT, float* __restrict__ ADJ, float* __restrict__ DEGO)
{
    __shared__ float Hs[4][DD];
    __shared__ int cnt_s[4];
    int t = threadIdx.x;
    int bid = blockIdx.x;

    if (bid < 256) {
        int b0 = bid << 2;
        {
            int d = t & 63, bl = t >> 6;
            const float* xr = x + (b0 + bl) * NN;
            float acc = benc[d];
            for (int n = 0; n < NN; n += 4) {
                float4 xv = *(const float4*)&xr[n];
                acc = fmaf(xv.x, Wenc[(n + 0) * DD + d], acc);
                acc = fmaf(xv.y, Wenc[(n + 1) * DD + d], acc);
                acc = fmaf(xv.z, Wenc[(n + 2) * DD + d], acc);
                acc = fmaf(xv.w, Wenc[(n + 3) * DD + d], acc);
            }
            Hs[bl][d] = fmaxf(acc, 0.0f);
        }
        __syncthreads();
        {
            int n = t;
            float mu[4], lv[4];
            float bm = bmu[n], bl_ = blv[n];
#pragma unroll
            for (int i = 0; i < 4; ++i) { mu[i] = bm; lv[i] = bl_; }
            for (int d = 0; d < DD; ++d) {
                float wm = Wmu[d * NN + n];
                float wl = Wlv[d * NN + n];
#pragma unroll
                for (int i = 0; i < 4; ++i) {
                    float h = Hs[i][d];
                    mu[i] = fmaf(h, wm, mu[i]);
                    lv[i] = fmaf(h, wl, lv[i]);
                }
            }
#pragma unroll
            for (int i = 0; i < 4; ++i) {
                int b = b0 + i;
                ZT[n * BB + b] = fmaf(eps[b * NN + n], expf(0.5f * lv[i]), mu[i]);
            }
        }
    } else {
        int nrow = bid - 256, m = t;
        float v = gl[nrow * NN + m];
        float a = (nrow == m) ? 1.0f : 1.0f / (1.0f + expf(-v));
        if (itp[0] > 50 && !(a > 0.1f)) a = 0.0f;
        ADJ[nrow * NN + m] = a;
        unsigned long long ball = __ballot(a != 0.0f);
        if ((m & 63) == 0) cnt_s[m >> 6] = __popcll(ball);
        __syncthreads();
        if (m == 0) DEGO[nrow] = (float)(cnt_s[0] + cnt_s[1] + cnt_s[2] + cnt_s[3]);
    }
}

// ============ kB: blocks 0-255 prepend k3b (1 col); all blocks: 2 k4 tiles ====
__global__ __launch_bounds__(256) void kB(
    const float* __restrict__ ZT, const float* __restrict__ embW,
    const float* __restrict__ embB, const float* __restrict__ g1W,
    const float* __restrict__ ADJ, const float* __restrict__ DEGO,
    float* __restrict__ ADJW, unsigned short* __restrict__ ADJWT,
    unsigned short* __restrict__ P1TT)
{
    __shared__ __align__(16) unsigned char smem[28160];
    int t = threadIdx.x;
    int bid = blockIdx.x;

    if (bid < 256) {
        // --- k3b: column bid -> ADJW f32 [n][m], ADJWT bf16 [m][n] ---
        int m = bid;
        int* cnt_s = (int*)smem;
        float* din_s = (float*)(smem + 16);
        float a = ADJ[t * NN + m];
        unsigned long long ball = __ballot(a != 0.0f);
        if ((t & 63) == 0) cnt_s[t >> 6] = __popcll(ball);
        __syncthreads();
        if (t == 0) din_s[0] = (float)(cnt_s[0] + cnt_s[1] + cnt_s[2] + cnt_s[3]);
        __syncthreads();
        float wv = a * (1.0f / sqrtf(DEGO[t])) * (1.0f / sqrtf(din_s[0]));
        ADJW[t * NN + m] = wv;
        ADJWT[m * NN + t] = f2bf(wv);
    }

    // --- k4: P1TT[j][n] = bf16( tanh(z*A+C) @ gc1_W ), 2 tiles/block ---
    {
        float (*As)[64] = (float(*)[64])(smem);
        float (*Cs)[64] = (float(*)[64])(smem + 1024);
        float (*zsm)[64] = (float(*)[64])(smem + 2048);
        float (*Ws)[68] = (float(*)[68])(smem + 3072);
        unsigned short (*Dst)[32][4] = (unsigned short(*)[32][4])(smem + 11776);
        int w = t >> 6, l = t & 63;
        int lo = l & 15, q = l >> 4;
        int q8 = q << 3;

        for (int i = t; i < 2048; i += 256) {
            int d = i >> 5, k = i & 31;
            Ws[k][d] = g1W[i];
        }
        __syncthreads();

        bf16x8 bwh[2][2], bwl[2][2];
#pragma unroll
        for (int nt = 0; nt < 2; ++nt)
#pragma unroll
            for (int kc = 0; kc < 2; ++kc) {
                float4 w0 = *(const float4*)&Ws[(nt << 4) + lo][(kc << 5) + q8];
                float4 w1 = *(const float4*)&Ws[(nt << 4) + lo][(kc << 5) + q8 + 4];
                float v[8] = {w0.x, w0.y, w0.z, w0.w, w1.x, w1.y, w1.z, w1.w};
                bf16x8 h, lq;
#pragma unroll
                for (int j = 0; j < 8; ++j) {
                    unsigned short hb = f2bf(v[j]);
                    h[j] = (short)hb;
                    lq[j] = (short)f2bf(v[j] - bf2f(hb));
                }
                bwh[nt][kc] = h;
                bwl[nt][kc] = lq;
            }

        for (int it = 0; it < 2; ++it) {
            int tile = (bid << 1) | it;
            int nb = tile & 63, bb2 = tile >> 6;
            int n0 = nb << 2, b0 = bb2 << 6;
            __syncthreads();
            {
                int ni = t >> 6, d = t & 63;
                size_t eb = (size_t)(n0 + ni) * (257 * 64);
                As[ni][d] = embW[eb + d];
                Cs[ni][d] = embW[eb + ((size_t)(n0 + ni + 1) << 6) + d]
                          + embB[((n0 + ni) << 6) + d];
                zsm[ni][d] = ZT[(size_t)(n0 + ni) * BB + b0 + d];
            }
            __syncthreads();
#pragma unroll
            for (int ni = 0; ni < 4; ++ni) {
                float zv = zsm[ni][(w << 4) + lo];
                f32x4 acc0 = (f32x4)0.0f, acc1 = (f32x4)0.0f;
#pragma unroll
                for (int kc = 0; kc < 2; ++kc) {
                    float4 a0 = *(const float4*)&As[ni][(kc << 5) + q8];
                    float4 a1 = *(const float4*)&As[ni][(kc << 5) + q8 + 4];
                    float4 c0 = *(const float4*)&Cs[ni][(kc << 5) + q8];
                    float4 c1 = *(const float4*)&Cs[ni][(kc << 5) + q8 + 4];
                    float e[8];
                    e[0] = ftanh(fmaf(zv, a0.x, c0.x));
                    e[1] = ftanh(fmaf(zv, a0.y, c0.y));
                    e[2] = ftanh(fmaf(zv, a0.z, c0.z));
                    e[3] = ftanh(fmaf(zv, a0.w, c0.w));
                    e[4] = ftanh(fmaf(zv, a1.x, c1.x));
                    e[5] = ftanh(fmaf(zv, a1.y, c1.y));
                    e[6] = ftanh(fmaf(zv, a1.z, c1.z));
                    e[7] = ftanh(fmaf(zv, a1.w, c1.w));
                    bf16x8 ehi, elo;
#pragma unroll
                    for (int j = 0; j < 8; ++j) {
                        unsigned short hb = f2bf(e[j]);
                        ehi[j] = (short)hb;
                        elo[j] = (short)f2bf(e[j] - bf2f(hb));
                    }
                    acc0 = __builtin_amdgcn_mfma_f32_16x16x32_bf16(ehi, bwh[0][kc], acc0, 0, 0, 0);
                    acc0 = __builtin_amdgcn_mfma_f32_16x16x32_bf16(elo, bwh[0][kc], acc0, 0, 0, 0);
                    acc0 = __builtin_amdgcn_mfma_f32_16x16x32_bf16(ehi, bwl[0][kc], acc0, 0, 0, 0);
                    acc1 = __builtin_amdgcn_mfma_f32_16x16x32_bf16(ehi, bwh[1][kc], acc1, 0, 0, 0);
                    acc1 = __builtin_amdgcn_mfma_f32_16x16x32_bf16(elo, bwh[1][kc], acc1, 0, 0, 0);
                    acc1 = __builtin_amdgcn_mfma_f32_16x16x32_bf16(ehi, bwl[1][kc], acc1, 0, 0, 0);
                }
                int bl = (w << 4) + (q << 2);
#pragma unroll
                for (int r = 0; r < 4; ++r) {
                    Dst[bl + r][lo][ni]      = f2bf(acc0[r]);
                    Dst[bl + r][16 + lo][ni] = f2bf(acc1[r]);
                }
            }
            __syncthreads();
            const uint2* dsp = (const uint2*)&Dst[0][0][0];
            size_t obase = ((size_t)b0 * 32) * NN + n0;
#pragma unroll
            for (int i = 0; i < 8; ++i) {
                int p = (i << 8) + t;
                uint2 v = dsp[p];
                *(uint2*)&P1TT[obase + (size_t)p * NN] = v;
            }
        }
    }
}

// ============ kCD: k5 (both m-halves -> Q rows in LDS) + k6 epilogue =========
// grid 512 = jt; block computes Q rows b=2jt,2jt+1 fully, then
// xhat[b][:] = Q[b][:] @ ADJW + g2b  (k-ascending FMA, bit-identical to kD)
__global__ __launch_bounds__(256) void kCD(
    const unsigned short* __restrict__ adjwt, const unsigned short* __restrict__ p1tt,
    const float* __restrict__ g1b, const float* __restrict__ g2w,
    const float* __restrict__ adjw, const float* __restrict__ g2b,
    float* __restrict__ xh)
{
    __shared__ float Qs[2][NN];
    int t = threadIdx.x;
    int w = t >> 6, l = t & 63;
    int c = l & 15, q = l >> 4;
    int jt = blockIdx.x;
    int j0 = jt << 6;
    int bb0 = jt << 1;

    float b1v0 = g1b[c],      g2v0 = g2w[c];
    float b1v1 = g1b[16 + c], g2v1 = g2w[16 + c];

    const unsigned short* bp[4];
#pragma unroll
    for (int ji = 0; ji < 4; ++ji)
        bp[ji] = p1tt + (size_t)(j0 + (ji << 4) + c) * NN + (q << 3);

#pragma unroll
    for (int mh = 0; mh < 2; ++mh) {
        int mbase = (mh << 7) + (w << 5);
        f32x4 acc[2][4];
#pragma unroll
        for (int i = 0; i < 2; ++i)
#pragma unroll
            for (int j = 0; j < 4; ++j) acc[i][j] = (f32x4)0.0f;

        const unsigned short* ap[2];
#pragma unroll
        for (int mi = 0; mi < 2; ++mi)
            ap[mi] = adjwt + (size_t)(mbase + (mi << 4) + c) * NN + (q << 3);

#pragma unroll 2
        for (int n0 = 0; n0 < NN; n0 += 32) {
            bf16x8 af[2], bf[4];
#pragma unroll
            for (int mi = 0; mi < 2; ++mi) af[mi] = *(const bf16x8*)(ap[mi] + n0);
#pragma unroll
            for (int ji = 0; ji < 4; ++ji) bf[ji] = *(const bf16x8*)(bp[ji] + n0);
#pragma unroll
            for (int mi = 0; mi < 2; ++mi)
#pragma unroll
                for (int ji = 0; ji < 4; ++ji)
                    acc[mi][ji] = __builtin_amdgcn_mfma_f32_16x16x32_bf16(
                        af[mi], bf[ji], acc[mi][ji], 0, 0, 0);
        }

#pragma unroll
        for (int mi = 0; mi < 2; ++mi) {
#pragma unroll
            for (int bb = 0; bb < 2; ++bb) {
                float red[4];
#pragma unroll
                for (int r = 0; r < 4; ++r) {
                    float s = ftanh(acc[mi][(bb << 1) + 0][r] + b1v0) * g2v0
                            + ftanh(acc[mi][(bb << 1) + 1][r] + b1v1) * g2v1;
                    s += __shfl_xor(s, 1);
                    s += __shfl_xor(s, 2);
                    s += __shfl_xor(s, 4);
                    s += __shfl_xor(s, 8);
                    red[r] = s;
                }
                float* qp = &Qs[bb][mbase + (mi << 4) + (q << 2)];
                if (c == 0) qp[0] = red[0];
                if (c == 1) qp[1] = red[1];
                if (c == 2) qp[2] = red[2];
                if (c == 3) qp[3] = red[3];
            }
        }
    }
    __syncthreads();

    // --- k6 epilogue: xhat rows bb0, bb0+1. thread t -> column m' = t.
    // k ascending 0..255, FMA — identical summation order to kD.
    {
        int mp = t;
        float a0 = 0.0f, a1 = 0.0f;
        for (int k = 0; k < NN; ++k) {
            float wv = adjw[k * NN + mp];
            a0 = fmaf(Qs[0][k], wv, a0);
            a1 = fmaf(Qs[1][k], wv, a1);
        }
        float bias = g2b[0];
        xh[(size_t)(bb0 + 0) * NN + mp] = a0 + bias;
        xh[(size_t)(bb0 + 1) * NN + mp] = a1 + bias;
    }
}

extern "C" void kernel_launch(void* const* d_in, const int* in_sizes, int n_in,
                              void* d_out, int out_size, void* d_ws, size_t ws_size,
                              hipStream_t stream) {
    const float* x    = (const float*)d_in[0];
    const float* eps  = (const float*)d_in[1];
    const float* gl   = (const float*)d_in[2];
    const float* Wenc = (const float*)d_in[3];
    const float* benc = (const float*)d_in[4];
    const float* Wmu  = (const float*)d_in[5];
    const float* bmu  = (const float*)d_in[6];
    const float* Wlv  = (const float*)d_in[7];
    const float* blv  = (const float*)d_in[8];
    const float* embW = (const float*)d_in[9];
    const float* embB = (const float*)d_in[10];
    const float* g1W  = (const float*)d_in[11];
    const float* g1b  = (const float*)d_in[12];
    const float* g2W  = (const float*)d_in[13];
    const float* g2b  = (const float*)d_in[14];
    const int*   itp  = (const int*)d_in[15];

    float* ws   = (float*)d_ws;
    float* ZT   = ws + 65536;
    float* ADJ  = ws + 327680;
    float* DEGO = ws + 393216;
    float* ADJW = ws + 393472;
    unsigned short* ADJWT = (unsigned short*)(ws + 459008);
    unsigned short* P1TT  = (unsigned short*)(ws + 491776);
    float* xh   = (float*)d_out;

    kA <<<512, 256, 0, stream>>>(x, eps, gl, Wenc, benc, Wmu, bmu, Wlv, blv,
                                 itp, ZT, ADJ, DEGO);
    kB <<<512, 256, 0, stream>>>(ZT, embW, embB, g1W, ADJ, DEGO, ADJW, ADJWT, P1TT);
    kCD<<<512, 256, 0, stream>>>(ADJWT, P1TT, g1b, g2W, ADJW, g2b, xh);
}